// Round 1
// baseline (846.740 us; speedup 1.0000x reference)
//
#include <hip/hip_runtime.h>

#define N_NODES 50000
#define N_EDGES 800000
#define IN_DIM 128
#define OUT_DIM 64
#define K_KERNELS 2

// order-preserving float <-> uint encoding for atomicMax on floats
__device__ __forceinline__ unsigned enc_f(float f) {
    unsigned b = __float_as_uint(f);
    return (b & 0x80000000u) ? ~b : (b | 0x80000000u);
}
__device__ __forceinline__ float dec_f(unsigned u) {
    return (u >= 0x80000000u) ? __uint_as_float(u ^ 0x80000000u)
                              : __uint_as_float(~u);
}

// ---------------------------------------------------------------------------
// Kernel A: wx[k][n][:] = x[n] @ W_k ; al/ar[k][n][s] = wx . w_{l,r}[k][s]
// one wave per (k,n); lane = output column
// ---------------------------------------------------------------------------
__global__ void transform_kernel(const float* __restrict__ x,
                                 const float* __restrict__ Wt,
                                 const float* __restrict__ wl,
                                 const float* __restrict__ wr,
                                 float* __restrict__ wx,
                                 float* __restrict__ al,
                                 float* __restrict__ ar) {
    int wid = blockIdx.x * 4 + (threadIdx.x >> 6);
    if (wid >= K_KERNELS * N_NODES) return;
    int lane = threadIdx.x & 63;
    int k = wid / N_NODES;
    int n = wid - k * N_NODES;
    const float* xr = x + (long long)n * IN_DIM;
    const float* Wk = Wt + k * IN_DIM * OUT_DIM;
    float acc = 0.f;
#pragma unroll 8
    for (int i = 0; i < IN_DIM; ++i)
        acc = fmaf(xr[i], Wk[i * OUT_DIM + lane], acc);
    wx[(long long)wid * OUT_DIM + lane] = acc;
#pragma unroll
    for (int s = 0; s < 3; ++s) {
        float pl = acc * wl[(k * 3 + s) * OUT_DIM + lane];
        float pr = acc * wr[(k * 3 + s) * OUT_DIM + lane];
#pragma unroll
        for (int off = 32; off > 0; off >>= 1) {
            pl += __shfl_xor(pl, off);
            pr += __shfl_xor(pr, off);
        }
        if (lane == 0) {
            al[wid * 3 + s] = pl;
            ar[wid * 3 + s] = pr;
        }
    }
}

// ---------------------------------------------------------------------------
// Kernel B: per (k,e) score + segment max (atomicMax on encoded float)
// ---------------------------------------------------------------------------
__global__ void score_kernel(const int* __restrict__ rows,
                             const int* __restrict__ cols,
                             const float* __restrict__ atten,
                             const float* __restrict__ support,
                             const float* __restrict__ al,
                             const float* __restrict__ ar,
                             float* __restrict__ scores,
                             unsigned* __restrict__ menc) {
    int tid = blockIdx.x * 256 + threadIdx.x;
    if (tid >= K_KERNELS * N_EDGES) return;
    int k = tid / N_EDGES;
    int e = tid - k * N_EDGES;
    int r = rows[e], c = cols[e];
    const float* alr = al + (k * N_NODES + r) * 3;
    const float* arc = ar + (k * N_NODES + c) * 3;
    float sc = (alr[0] + arc[0]) * atten[e]
             + (alr[1] + arc[1]) * atten[N_EDGES + e]
             + (alr[2] + arc[2]) * support[k * N_EDGES + e];
    scores[tid] = sc;
    atomicMax(&menc[k * N_NODES + r], enc_f(sc));
}

// ---------------------------------------------------------------------------
// Kernel C: ex = exp(score - m[row]); denom[row] += ex
// ---------------------------------------------------------------------------
__global__ void exp_kernel(const int* __restrict__ rows,
                           const unsigned* __restrict__ menc,
                           float* __restrict__ scores,
                           float* __restrict__ denom) {
    int tid = blockIdx.x * 256 + threadIdx.x;
    if (tid >= K_KERNELS * N_EDGES) return;
    int k = tid / N_EDGES;
    int e = tid - k * N_EDGES;
    int r = rows[e];
    float m = dec_f(menc[k * N_NODES + r]);
    float ex = __expf(scores[tid] - m);
    scores[tid] = ex;
    atomicAdd(&denom[k * N_NODES + r], ex);
}

// ---------------------------------------------------------------------------
// Kernel D: acc[row][:] += (ex/denom[row]) * wx[k][col][:]  (one wave/edge)
// ---------------------------------------------------------------------------
__global__ void spmm_kernel(const int* __restrict__ rows,
                            const int* __restrict__ cols,
                            const float* __restrict__ scores,
                            const float* __restrict__ denom,
                            const float* __restrict__ wx,
                            float* __restrict__ acc) {
    int wid = blockIdx.x * 4 + (threadIdx.x >> 6);
    if (wid >= K_KERNELS * N_EDGES) return;
    int lane = threadIdx.x & 63;
    int k = wid / N_EDGES;
    int e = wid - k * N_EDGES;
    int r = rows[e], c = cols[e];
    float p = scores[wid] / denom[k * N_NODES + r];
    float v = wx[((long long)(k * N_NODES + c)) * OUT_DIM + lane];
    atomicAdd(&acc[(long long)r * OUT_DIM + lane], p * v);
}

// ---------------------------------------------------------------------------
// Kernel E: out = elu([x, acc] @ Wres)   (one wave per row; lane = out col)
// ---------------------------------------------------------------------------
__global__ void residual_kernel(const float* __restrict__ x,
                                const float* __restrict__ acc,
                                const float* __restrict__ Wres,
                                float* __restrict__ out) {
    int wid = blockIdx.x * 4 + (threadIdx.x >> 6);
    if (wid >= N_NODES) return;
    int lane = threadIdx.x & 63;
    const float* xr = x + (long long)wid * IN_DIM;
    float r = 0.f;
#pragma unroll 8
    for (int i = 0; i < IN_DIM; ++i)
        r = fmaf(xr[i], Wres[i * OUT_DIM + lane], r);
    const float* accr = acc + (long long)wid * OUT_DIM;
#pragma unroll 8
    for (int d = 0; d < OUT_DIM; ++d)
        r = fmaf(accr[d], Wres[(IN_DIM + d) * OUT_DIM + lane], r);
    out[(long long)wid * OUT_DIM + lane] = (r > 0.f) ? r : expm1f(r);
}

extern "C" void kernel_launch(void* const* d_in, const int* in_sizes, int n_in,
                              void* d_out, int out_size, void* d_ws, size_t ws_size,
                              hipStream_t stream) {
    const float* x       = (const float*)d_in[0];
    const float* support = (const float*)d_in[1];
    const float* atten   = (const float*)d_in[2];
    const float* Wt      = (const float*)d_in[3];
    const float* wl      = (const float*)d_in[4];
    const float* wr      = (const float*)d_in[5];
    const float* Wres    = (const float*)d_in[6];
    const int*   rows    = (const int*)d_in[7];
    const int*   cols    = (const int*)d_in[8];
    float* out = (float*)d_out;

    // workspace layout (floats/uints, all 4-byte)
    float*    wx     = (float*)d_ws;                                   // K*N*64
    float*    al     = wx + (size_t)K_KERNELS * N_NODES * OUT_DIM;     // K*N*3
    float*    ar     = al + (size_t)K_KERNELS * N_NODES * 3;           // K*N*3
    float*    scores = ar + (size_t)K_KERNELS * N_NODES * 3;           // K*E
    unsigned* menc   = (unsigned*)(scores + (size_t)K_KERNELS * N_EDGES); // K*N
    float*    denom  = (float*)(menc + (size_t)K_KERNELS * N_NODES);   // K*N
    float*    acc    = denom + (size_t)K_KERNELS * N_NODES;            // N*64

    // zero {menc, denom, acc} (contiguous) every call
    size_t zbytes = ((size_t)K_KERNELS * N_NODES * 2 + (size_t)N_NODES * OUT_DIM) * 4;
    hipMemsetAsync(menc, 0, zbytes, stream);

    transform_kernel<<<(K_KERNELS * N_NODES + 3) / 4, 256, 0, stream>>>(
        x, Wt, wl, wr, wx, al, ar);
    score_kernel<<<(K_KERNELS * N_EDGES + 255) / 256, 256, 0, stream>>>(
        rows, cols, atten, support, al, ar, scores, menc);
    exp_kernel<<<(K_KERNELS * N_EDGES + 255) / 256, 256, 0, stream>>>(
        rows, menc, scores, denom);
    spmm_kernel<<<(K_KERNELS * N_EDGES + 3) / 4, 256, 0, stream>>>(
        rows, cols, scores, denom, wx, acc);
    residual_kernel<<<(N_NODES + 3) / 4, 256, 0, stream>>>(
        x, acc, Wres, out);
}

// Round 2
// 762.828 us; speedup vs baseline: 1.1100x; 1.1100x over previous
//
#include <hip/hip_runtime.h>

#define N_NODES 50000
#define N_EDGES 800000
#define IN_DIM 128
#define OUT_DIM 64
#define K_KERNELS 2
#define NEG_INF (-1e30f)

// ---------------------------------------------------------------------------
// Kernel A: wx[k][n][:] = x[n] @ W_k ; al/ar[k][n][s] = wx . w_{l,r}[k][s]
// one wave per (k,n); lane = output column
// ---------------------------------------------------------------------------
__global__ void transform_kernel(const float* __restrict__ x,
                                 const float* __restrict__ Wt,
                                 const float* __restrict__ wl,
                                 const float* __restrict__ wr,
                                 float* __restrict__ wx,
                                 float* __restrict__ al,
                                 float* __restrict__ ar) {
    int wid = blockIdx.x * 4 + (threadIdx.x >> 6);
    if (wid >= K_KERNELS * N_NODES) return;
    int lane = threadIdx.x & 63;
    int k = wid / N_NODES;
    int n = wid - k * N_NODES;
    const float* xr = x + (long long)n * IN_DIM;
    const float* Wk = Wt + k * IN_DIM * OUT_DIM;
    float acc = 0.f;
#pragma unroll 8
    for (int i = 0; i < IN_DIM; ++i)
        acc = fmaf(xr[i], Wk[i * OUT_DIM + lane], acc);
    wx[(long long)wid * OUT_DIM + lane] = acc;
#pragma unroll
    for (int s = 0; s < 3; ++s) {
        float pl = acc * wl[(k * 3 + s) * OUT_DIM + lane];
        float pr = acc * wr[(k * 3 + s) * OUT_DIM + lane];
#pragma unroll
        for (int off = 32; off > 0; off >>= 1) {
            pl += __shfl_xor(pl, off);
            pr += __shfl_xor(pr, off);
        }
        if (lane == 0) {
            al[wid * 3 + s] = pl;
            ar[wid * 3 + s] = pr;
        }
    }
}

// ---------------------------------------------------------------------------
// CSR build: histogram -> single-block scan -> scatter
// ---------------------------------------------------------------------------
__global__ void hist_kernel(const int* __restrict__ rows, int* __restrict__ deg) {
    int e = blockIdx.x * 256 + threadIdx.x;
    if (e >= N_EDGES) return;
    atomicAdd(&deg[rows[e]], 1);
}

__global__ void scan_kernel(const int* __restrict__ deg,
                            int* __restrict__ row_ptr,
                            int* __restrict__ cursor) {
    __shared__ int sums[256];
    const int CH = (N_NODES + 255) / 256;
    int t = threadIdx.x;
    int base = t * CH;
    int s = 0;
    for (int i = 0; i < CH; ++i) {
        int r = base + i;
        if (r < N_NODES) s += deg[r];
    }
    sums[t] = s;
    __syncthreads();
    if (t == 0) {
        int a = 0;
        for (int i = 0; i < 256; ++i) { int v = sums[i]; sums[i] = a; a += v; }
    }
    __syncthreads();
    int off = sums[t];
    for (int i = 0; i < CH; ++i) {
        int r = base + i;
        if (r < N_NODES) { row_ptr[r] = off; cursor[r] = off; off += deg[r]; }
    }
    if (t == 0) row_ptr[N_NODES] = N_EDGES;
}

__global__ void scatter_kernel(const int* __restrict__ rows,
                               const int* __restrict__ cols,
                               int* __restrict__ cursor,
                               int* __restrict__ perm,
                               int* __restrict__ cols_s) {
    int e = blockIdx.x * 256 + threadIdx.x;
    if (e >= N_EDGES) return;
    int r = rows[e];
    int pos = atomicAdd(&cursor[r], 1);
    perm[pos] = e;
    cols_s[pos] = cols[e];
}

// ---------------------------------------------------------------------------
// Softmax per (k,row): one wave; online softmax over edge chunks of 64.
// probs[k*E + pos] ends up holding exp(s-m)/l in CSR (sorted) order.
// ---------------------------------------------------------------------------
__global__ void softmax_kernel(const int* __restrict__ row_ptr,
                               const int* __restrict__ perm,
                               const int* __restrict__ cols_s,
                               const float* __restrict__ atten,
                               const float* __restrict__ support,
                               const float* __restrict__ al,
                               const float* __restrict__ ar,
                               float* __restrict__ probs) {
    int wid = blockIdx.x * 4 + (threadIdx.x >> 6);
    if (wid >= K_KERNELS * N_NODES) return;
    int lane = threadIdx.x & 63;
    int k = wid / N_NODES;
    int r = wid - k * N_NODES;
    int beg = row_ptr[r], end = row_ptr[r + 1];
    if (beg == end) return;

    const float* alr = al + (size_t)(k * N_NODES + r) * 3;
    float al0 = alr[0], al1 = alr[1], al2 = alr[2];
    const float* ark = ar + (size_t)k * N_NODES * 3;
    const float* supk = support + (size_t)k * N_EDGES;
    float* pk = probs + (size_t)k * N_EDGES;

    float m = NEG_INF, l = 0.f;
    for (int base = beg; base < end; base += 64) {
        int pos = base + lane;
        bool valid = pos < end;
        float sc = NEG_INF;
        if (valid) {
            int e = perm[pos];
            int c = cols_s[pos];
            const float* arc = ark + (size_t)c * 3;
            sc = (al0 + arc[0]) * atten[e]
               + (al1 + arc[1]) * atten[N_EDGES + e]
               + (al2 + arc[2]) * supk[e];
            pk[pos] = sc;
        }
        float cm = sc;
#pragma unroll
        for (int off = 32; off > 0; off >>= 1)
            cm = fmaxf(cm, __shfl_xor(cm, off));
        float mn = fmaxf(m, cm);
        float ex = valid ? __expf(sc - mn) : 0.f;
#pragma unroll
        for (int off = 32; off > 0; off >>= 1)
            ex += __shfl_xor(ex, off);
        l = l * __expf(m - mn) + ex;
        m = mn;
    }
    float inv_l = 1.f / l;
    for (int base = beg; base < end; base += 64) {
        int pos = base + lane;
        if (pos < end) {
            float sc = pk[pos];
            pk[pos] = __expf(sc - m) * inv_l;
        }
    }
}

// ---------------------------------------------------------------------------
// SpMM: one wave per row; lane = out dim; register accumulation over both k.
// ---------------------------------------------------------------------------
__global__ void spmm_kernel(const int* __restrict__ row_ptr,
                            const int* __restrict__ cols_s,
                            const float* __restrict__ probs,
                            const float* __restrict__ wx,
                            float* __restrict__ acc) {
    int wid = blockIdx.x * 4 + (threadIdx.x >> 6);
    if (wid >= N_NODES) return;
    int lane = threadIdx.x & 63;
    int beg = row_ptr[wid], end = row_ptr[wid + 1];
    float a = 0.f;
#pragma unroll
    for (int k = 0; k < K_KERNELS; ++k) {
        const float* wxk = wx + (size_t)k * N_NODES * OUT_DIM;
        const float* pk = probs + (size_t)k * N_EDGES;
        for (int pos = beg; pos < end; ++pos) {
            float p = pk[pos];
            int c = cols_s[pos];
            a = fmaf(p, wxk[(size_t)c * OUT_DIM + lane], a);
        }
    }
    acc[(size_t)wid * OUT_DIM + lane] = a;
}

// ---------------------------------------------------------------------------
// Residual: out = elu([x, acc] @ Wres)
// ---------------------------------------------------------------------------
__global__ void residual_kernel(const float* __restrict__ x,
                                const float* __restrict__ acc,
                                const float* __restrict__ Wres,
                                float* __restrict__ out) {
    int wid = blockIdx.x * 4 + (threadIdx.x >> 6);
    if (wid >= N_NODES) return;
    int lane = threadIdx.x & 63;
    const float* xr = x + (long long)wid * IN_DIM;
    float r = 0.f;
#pragma unroll 8
    for (int i = 0; i < IN_DIM; ++i)
        r = fmaf(xr[i], Wres[i * OUT_DIM + lane], r);
    const float* accr = acc + (long long)wid * OUT_DIM;
#pragma unroll 8
    for (int d = 0; d < OUT_DIM; ++d)
        r = fmaf(accr[d], Wres[(IN_DIM + d) * OUT_DIM + lane], r);
    out[(long long)wid * OUT_DIM + lane] = (r > 0.f) ? r : expm1f(r);
}

extern "C" void kernel_launch(void* const* d_in, const int* in_sizes, int n_in,
                              void* d_out, int out_size, void* d_ws, size_t ws_size,
                              hipStream_t stream) {
    const float* x       = (const float*)d_in[0];
    const float* support = (const float*)d_in[1];
    const float* atten   = (const float*)d_in[2];
    const float* Wt      = (const float*)d_in[3];
    const float* wl      = (const float*)d_in[4];
    const float* wr      = (const float*)d_in[5];
    const float* Wres    = (const float*)d_in[6];
    const int*   rows    = (const int*)d_in[7];
    const int*   cols    = (const int*)d_in[8];
    float* out = (float*)d_out;

    // workspace layout (all 4-byte elements)
    float* wx      = (float*)d_ws;                                     // K*N*64
    float* al      = wx + (size_t)K_KERNELS * N_NODES * OUT_DIM;       // K*N*3
    float* ar      = al + (size_t)K_KERNELS * N_NODES * 3;             // K*N*3
    float* probs   = ar + (size_t)K_KERNELS * N_NODES * 3;             // K*E
    float* acc     = probs + (size_t)K_KERNELS * N_EDGES;              // N*64
    int*   deg     = (int*)(acc + (size_t)N_NODES * OUT_DIM);          // N
    int*   row_ptr = deg + N_NODES;                                    // N+1
    int*   cursor  = row_ptr + N_NODES + 1;                            // N
    int*   perm    = cursor + N_NODES;                                 // E
    int*   cols_s  = perm + N_EDGES;                                   // E

    // zero the degree histogram each call
    hipMemsetAsync(deg, 0, (size_t)N_NODES * sizeof(int), stream);

    transform_kernel<<<(K_KERNELS * N_NODES + 3) / 4, 256, 0, stream>>>(
        x, Wt, wl, wr, wx, al, ar);
    hist_kernel<<<(N_EDGES + 255) / 256, 256, 0, stream>>>(rows, deg);
    scan_kernel<<<1, 256, 0, stream>>>(deg, row_ptr, cursor);
    scatter_kernel<<<(N_EDGES + 255) / 256, 256, 0, stream>>>(
        rows, cols, cursor, perm, cols_s);
    softmax_kernel<<<(K_KERNELS * N_NODES + 3) / 4, 256, 0, stream>>>(
        row_ptr, perm, cols_s, atten, support, al, ar, probs);
    spmm_kernel<<<(N_NODES + 3) / 4, 256, 0, stream>>>(
        row_ptr, cols_s, probs, wx, acc);
    residual_kernel<<<(N_NODES + 3) / 4, 256, 0, stream>>>(
        x, acc, Wres, out);
}

// Round 3
// 354.809 us; speedup vs baseline: 2.3865x; 2.1500x over previous
//
#include <hip/hip_runtime.h>

#define N_NODES 50000
#define N_EDGES 800000
#define IN_DIM 128
#define OUT_DIM 64
#define K_KERNELS 2
#define NEG_INF (-1e30f)
#define TM 64
#define TK 32
#define NBLK ((N_NODES + TM - 1) / TM)       // 782
#define NB_SCAN ((N_NODES + 255) / 256)      // 196

// ---------------------------------------------------------------------------
// Tiled f32 GEMM: out[n][c] = sum_i x[n][i] * W[i][c] for 3 weight matrices
// mat 0,1: W_transform[k] -> wx[k]; mat 2: W_residual[:128] -> xres
// ---------------------------------------------------------------------------
__global__ __launch_bounds__(256) void gemm_kernel(
        const float* __restrict__ x,
        const float* __restrict__ Wt,
        const float* __restrict__ Wres,
        float* __restrict__ wx,
        float* __restrict__ xres) {
    __shared__ float As[TK][TM + 1];   // x tile, transposed, padded
    __shared__ float Bs[TK][OUT_DIM];  // W tile
    int g = blockIdx.x;
    int mat = g / NBLK;
    int nb = g - mat * NBLK;
    int n0 = nb * TM;
    const float* W = (mat < 2) ? (Wt + (size_t)mat * IN_DIM * OUT_DIM) : Wres;
    float* out = (mat < 2) ? (wx + (size_t)mat * N_NODES * OUT_DIM) : xres;

    int tid = threadIdx.x;
    int tr = tid >> 4;   // 0..15 node group
    int tc = tid & 15;   // 0..15 col group

    float acc[4][4] = {};
    for (int kt = 0; kt < IN_DIM; kt += TK) {
        // stage A: x[n0+n][kt+kk] -> As[kk][n]  (64 nodes x 32 k = 512 float4)
        for (int l = tid; l < TM * (TK / 4); l += 256) {
            int n = l >> 3;
            int k4 = (l & 7) << 2;
            int gn = n0 + n;
            float4 v = make_float4(0.f, 0.f, 0.f, 0.f);
            if (gn < N_NODES)
                v = *(const float4*)(x + (size_t)gn * IN_DIM + kt + k4);
            As[k4 + 0][n] = v.x;
            As[k4 + 1][n] = v.y;
            As[k4 + 2][n] = v.z;
            As[k4 + 3][n] = v.w;
        }
        // stage B: W[kt+kk][c] -> Bs[kk][c]  (32 x 64 floats, contiguous)
        for (int l = tid; l < TK * (OUT_DIM / 4); l += 256) {
            int kk = l >> 4;
            int c4 = (l & 15) << 2;
            *(float4*)&Bs[kk][c4] =
                *(const float4*)(W + (size_t)(kt + kk) * OUT_DIM + c4);
        }
        __syncthreads();
#pragma unroll
        for (int kk = 0; kk < TK; ++kk) {
            float4 a = *(const float4*)&As[kk][tr * 4];
            float4 b = *(const float4*)&Bs[kk][tc * 4];
            float av[4] = {a.x, a.y, a.z, a.w};
            float bv[4] = {b.x, b.y, b.z, b.w};
#pragma unroll
            for (int i = 0; i < 4; ++i)
#pragma unroll
                for (int j = 0; j < 4; ++j)
                    acc[i][j] = fmaf(av[i], bv[j], acc[i][j]);
        }
        __syncthreads();
    }
#pragma unroll
    for (int i = 0; i < 4; ++i) {
        int gn = n0 + tr * 4 + i;
        if (gn < N_NODES)
            *(float4*)(out + (size_t)gn * OUT_DIM + tc * 4) =
                make_float4(acc[i][0], acc[i][1], acc[i][2], acc[i][3]);
    }
}

// ---------------------------------------------------------------------------
// al/ar: one wave per (k,n); lane = col; 6 dot products via shfl reduce
// ---------------------------------------------------------------------------
__global__ void alr_kernel(const float* __restrict__ wx,
                           const float* __restrict__ wl,
                           const float* __restrict__ wr,
                           float* __restrict__ al,
                           float* __restrict__ ar) {
    int wid = blockIdx.x * 4 + (threadIdx.x >> 6);
    if (wid >= K_KERNELS * N_NODES) return;
    int lane = threadIdx.x & 63;
    int k = wid / N_NODES;
    float v = wx[(size_t)wid * OUT_DIM + lane];
#pragma unroll
    for (int s = 0; s < 3; ++s) {
        float pl = v * wl[(k * 3 + s) * OUT_DIM + lane];
        float pr = v * wr[(k * 3 + s) * OUT_DIM + lane];
#pragma unroll
        for (int off = 32; off > 0; off >>= 1) {
            pl += __shfl_xor(pl, off);
            pr += __shfl_xor(pr, off);
        }
        if (lane == 0) {
            al[wid * 3 + s] = pl;
            ar[wid * 3 + s] = pr;
        }
    }
}

// ---------------------------------------------------------------------------
// CSR build: histogram -> 3-phase parallel scan -> scatter
// ---------------------------------------------------------------------------
__global__ void hist_kernel(const int* __restrict__ rows, int* __restrict__ deg) {
    int e = blockIdx.x * 256 + threadIdx.x;
    if (e >= N_EDGES) return;
    atomicAdd(&deg[rows[e]], 1);
}

__global__ void scan1_kernel(const int* __restrict__ deg, int* __restrict__ bsum) {
    __shared__ int sh[256];
    int t = threadIdx.x;
    int i = blockIdx.x * 256 + t;
    sh[t] = (i < N_NODES) ? deg[i] : 0;
    __syncthreads();
    for (int off = 128; off > 0; off >>= 1) {
        if (t < off) sh[t] += sh[t + off];
        __syncthreads();
    }
    if (t == 0) bsum[blockIdx.x] = sh[0];
}

__global__ void scan2_kernel(int* __restrict__ bsum, int* __restrict__ row_ptr) {
    __shared__ int sh[256];
    int t = threadIdx.x;
    sh[t] = (t < NB_SCAN) ? bsum[t] : 0;
    __syncthreads();
    if (t == 0) {
        int a = 0;
        for (int i = 0; i < NB_SCAN; ++i) { int v = sh[i]; sh[i] = a; a += v; }
        row_ptr[N_NODES] = N_EDGES;
    }
    __syncthreads();
    if (t < NB_SCAN) bsum[t] = sh[t];
}

__global__ void scan3_kernel(const int* __restrict__ deg,
                             const int* __restrict__ bpre,
                             int* __restrict__ row_ptr,
                             int* __restrict__ cursor) {
    __shared__ int sh[256];
    int t = threadIdx.x;
    int i = blockIdx.x * 256 + t;
    int v = (i < N_NODES) ? deg[i] : 0;
    sh[t] = v;
    int val = v;
    __syncthreads();
    for (int off = 1; off < 256; off <<= 1) {
        int y = (t >= off) ? sh[t - off] : 0;
        __syncthreads();
        val += y;
        sh[t] = val;
        __syncthreads();
    }
    if (i < N_NODES) {
        int rp = bpre[blockIdx.x] + val - v;   // exclusive prefix
        row_ptr[i] = rp;
        cursor[i] = rp;
    }
}

__global__ void scatter_kernel(const int* __restrict__ rows,
                               const int* __restrict__ cols,
                               int* __restrict__ cursor,
                               int* __restrict__ perm,
                               int* __restrict__ cols_s) {
    int e = blockIdx.x * 256 + threadIdx.x;
    if (e >= N_EDGES) return;
    int r = rows[e];
    int pos = atomicAdd(&cursor[r], 1);
    perm[pos] = e;
    cols_s[pos] = cols[e];
}

// ---------------------------------------------------------------------------
// Softmax per (k,row): one wave; register fast path for deg <= 64
// ---------------------------------------------------------------------------
__global__ void softmax_kernel(const int* __restrict__ row_ptr,
                               const int* __restrict__ perm,
                               const int* __restrict__ cols_s,
                               const float* __restrict__ atten,
                               const float* __restrict__ support,
                               const float* __restrict__ al,
                               const float* __restrict__ ar,
                               float* __restrict__ probs) {
    int wid = blockIdx.x * 4 + (threadIdx.x >> 6);
    if (wid >= K_KERNELS * N_NODES) return;
    int lane = threadIdx.x & 63;
    int k = wid / N_NODES;
    int r = wid - k * N_NODES;
    int beg = row_ptr[r], end = row_ptr[r + 1];
    if (beg == end) return;

    const float* alr = al + (size_t)(k * N_NODES + r) * 3;
    float al0 = alr[0], al1 = alr[1], al2 = alr[2];
    const float* ark = ar + (size_t)k * N_NODES * 3;
    const float* supk = support + (size_t)k * N_EDGES;
    float* pk = probs + (size_t)k * N_EDGES;

    if (end - beg <= 64) {
        int pos = beg + lane;
        bool valid = pos < end;
        float sc = NEG_INF;
        if (valid) {
            int e = perm[pos];
            int c = cols_s[pos];
            const float* arc = ark + (size_t)c * 3;
            sc = (al0 + arc[0]) * atten[e]
               + (al1 + arc[1]) * atten[N_EDGES + e]
               + (al2 + arc[2]) * supk[e];
        }
        float m = sc;
#pragma unroll
        for (int off = 32; off > 0; off >>= 1)
            m = fmaxf(m, __shfl_xor(m, off));
        float ex = valid ? __expf(sc - m) : 0.f;
        float l = ex;
#pragma unroll
        for (int off = 32; off > 0; off >>= 1)
            l += __shfl_xor(l, off);
        if (valid) pk[pos] = ex / l;
        return;
    }

    // long-row path (rare)
    float m = NEG_INF, l = 0.f;
    for (int base = beg; base < end; base += 64) {
        int pos = base + lane;
        bool valid = pos < end;
        float sc = NEG_INF;
        if (valid) {
            int e = perm[pos];
            int c = cols_s[pos];
            const float* arc = ark + (size_t)c * 3;
            sc = (al0 + arc[0]) * atten[e]
               + (al1 + arc[1]) * atten[N_EDGES + e]
               + (al2 + arc[2]) * supk[e];
            pk[pos] = sc;
        }
        float cm = sc;
#pragma unroll
        for (int off = 32; off > 0; off >>= 1)
            cm = fmaxf(cm, __shfl_xor(cm, off));
        float mn = fmaxf(m, cm);
        float ex = valid ? __expf(sc - mn) : 0.f;
#pragma unroll
        for (int off = 32; off > 0; off >>= 1)
            ex += __shfl_xor(ex, off);
        l = l * __expf(m - mn) + ex;
        m = mn;
    }
    float inv_l = 1.f / l;
    for (int base = beg; base < end; base += 64) {
        int pos = base + lane;
        if (pos < end)
            pk[pos] = __expf(pk[pos] - m) * inv_l;
    }
}

// ---------------------------------------------------------------------------
// SpMM: one wave per row; lane = out col; 4-way unrolled gather
// ---------------------------------------------------------------------------
__global__ void spmm_kernel(const int* __restrict__ row_ptr,
                            const int* __restrict__ cols_s,
                            const float* __restrict__ probs,
                            const float* __restrict__ wx,
                            float* __restrict__ acc) {
    int wid = blockIdx.x * 4 + (threadIdx.x >> 6);
    if (wid >= N_NODES) return;
    int lane = threadIdx.x & 63;
    int beg = row_ptr[wid], end = row_ptr[wid + 1];
    float a0 = 0.f, a1 = 0.f, a2 = 0.f, a3 = 0.f;
#pragma unroll
    for (int k = 0; k < K_KERNELS; ++k) {
        const float* wxk = wx + (size_t)k * N_NODES * OUT_DIM;
        const float* pk = probs + (size_t)k * N_EDGES;
        int pos = beg;
        for (; pos + 4 <= end; pos += 4) {
            int c0 = cols_s[pos], c1 = cols_s[pos + 1];
            int c2 = cols_s[pos + 2], c3 = cols_s[pos + 3];
            float p0 = pk[pos], p1 = pk[pos + 1];
            float p2 = pk[pos + 2], p3 = pk[pos + 3];
            a0 = fmaf(p0, wxk[(size_t)c0 * OUT_DIM + lane], a0);
            a1 = fmaf(p1, wxk[(size_t)c1 * OUT_DIM + lane], a1);
            a2 = fmaf(p2, wxk[(size_t)c2 * OUT_DIM + lane], a2);
            a3 = fmaf(p3, wxk[(size_t)c3 * OUT_DIM + lane], a3);
        }
        for (; pos < end; ++pos)
            a0 = fmaf(pk[pos], wxk[(size_t)cols_s[pos] * OUT_DIM + lane], a0);
    }
    acc[(size_t)wid * OUT_DIM + lane] = (a0 + a1) + (a2 + a3);
}

// ---------------------------------------------------------------------------
// Residual tail: out = elu(xres + acc @ Wres[128:]); acc row via shfl bcast
// ---------------------------------------------------------------------------
__global__ void residual_kernel(const float* __restrict__ xres,
                                const float* __restrict__ acc,
                                const float* __restrict__ Wres,
                                float* __restrict__ out) {
    int wid = blockIdx.x * 4 + (threadIdx.x >> 6);
    if (wid >= N_NODES) return;
    int lane = threadIdx.x & 63;
    const float* Wres2 = Wres + (size_t)IN_DIM * OUT_DIM;
    float accv = acc[(size_t)wid * OUT_DIM + lane];
    float r = xres[(size_t)wid * OUT_DIM + lane];
#pragma unroll 8
    for (int d = 0; d < OUT_DIM; ++d) {
        float ad = __shfl(accv, d);
        r = fmaf(ad, Wres2[d * OUT_DIM + lane], r);
    }
    out[(size_t)wid * OUT_DIM + lane] = (r > 0.f) ? r : expm1f(r);
}

extern "C" void kernel_launch(void* const* d_in, const int* in_sizes, int n_in,
                              void* d_out, int out_size, void* d_ws, size_t ws_size,
                              hipStream_t stream) {
    const float* x       = (const float*)d_in[0];
    const float* support = (const float*)d_in[1];
    const float* atten   = (const float*)d_in[2];
    const float* Wt      = (const float*)d_in[3];
    const float* wl      = (const float*)d_in[4];
    const float* wr      = (const float*)d_in[5];
    const float* Wres    = (const float*)d_in[6];
    const int*   rows    = (const int*)d_in[7];
    const int*   cols    = (const int*)d_in[8];
    float* out = (float*)d_out;

    // workspace layout (all 4-byte elements)
    float* wx      = (float*)d_ws;                                     // K*N*64
    float* xres    = wx + (size_t)K_KERNELS * N_NODES * OUT_DIM;       // N*64
    float* al      = xres + (size_t)N_NODES * OUT_DIM;                 // K*N*3
    float* ar      = al + (size_t)K_KERNELS * N_NODES * 3;             // K*N*3
    float* probs   = ar + (size_t)K_KERNELS * N_NODES * 3;             // K*E
    float* acc     = probs + (size_t)K_KERNELS * N_EDGES;              // N*64
    int*   deg     = (int*)(acc + (size_t)N_NODES * OUT_DIM);          // N
    int*   row_ptr = deg + N_NODES;                                    // N+1
    int*   cursor  = row_ptr + N_NODES + 1;                            // N
    int*   perm    = cursor + N_NODES;                                 // E
    int*   cols_s  = perm + N_EDGES;                                   // E
    int*   bsum    = cols_s + N_EDGES;                                 // NB_SCAN

    hipMemsetAsync(deg, 0, (size_t)N_NODES * sizeof(int), stream);

    gemm_kernel<<<3 * NBLK, 256, 0, stream>>>(x, Wt, Wres, wx, xres);
    hist_kernel<<<(N_EDGES + 255) / 256, 256, 0, stream>>>(rows, deg);
    scan1_kernel<<<NB_SCAN, 256, 0, stream>>>(deg, bsum);
    scan2_kernel<<<1, 256, 0, stream>>>(bsum, row_ptr);
    scan3_kernel<<<NB_SCAN, 256, 0, stream>>>(deg, bsum, row_ptr, cursor);
    scatter_kernel<<<(N_EDGES + 255) / 256, 256, 0, stream>>>(
        rows, cols, cursor, perm, cols_s);
    alr_kernel<<<(K_KERNELS * N_NODES + 3) / 4, 256, 0, stream>>>(
        wx, wl, wr, al, ar);
    softmax_kernel<<<(K_KERNELS * N_NODES + 3) / 4, 256, 0, stream>>>(
        row_ptr, perm, cols_s, atten, support, al, ar, probs);
    spmm_kernel<<<(N_NODES + 3) / 4, 256, 0, stream>>>(
        row_ptr, cols_s, probs, wx, acc);
    residual_kernel<<<(N_NODES + 3) / 4, 256, 0, stream>>>(
        xres, acc, Wres, out);
}

// Round 4
// 229.073 us; speedup vs baseline: 3.6964x; 1.5489x over previous
//
#include <hip/hip_runtime.h>

#define N_NODES 50000
#define N_EDGES 800000
#define IN_DIM 128
#define OUT_DIM 64
#define K_KERNELS 2
#define NEG_INF (-1e30f)
#define TM 64
#define TK 32
#define NBLK ((N_NODES + TM - 1) / TM)       // 782
#define NB_SCAN ((N_NODES + 255) / 256)      // 196

typedef unsigned short ushort_t;

__device__ __forceinline__ ushort_t f2bf(float f) {
    unsigned u = __float_as_uint(f);
    u += 0x7fffu + ((u >> 16) & 1u);         // round-to-nearest-even
    return (ushort_t)(u >> 16);
}
__device__ __forceinline__ float bf2f(ushort_t h) {
    return __uint_as_float((unsigned)h << 16);
}

// ---------------------------------------------------------------------------
// Tiled f32 GEMM over 3 weight mats. mat 0,1: W_transform[k] -> wxh (bf16)
// with al/ar fused epilogue; mat 2: W_residual[:128] -> xres (f32).
// ---------------------------------------------------------------------------
__global__ __launch_bounds__(256) void gemm_kernel(
        const float* __restrict__ x,
        const float* __restrict__ Wt,
        const float* __restrict__ Wres,
        const float* __restrict__ wl,
        const float* __restrict__ wr,
        ushort_t* __restrict__ wxh,
        float* __restrict__ xres,
        float* __restrict__ al,
        float* __restrict__ ar) {
    __shared__ float As[TK][TM];       // x tile, transposed (16B-aligned rows)
    __shared__ float Bs[TK][OUT_DIM];  // W tile
    int g = blockIdx.x;
    int mat = g / NBLK;
    int nb = g - mat * NBLK;
    int n0 = nb * TM;
    const float* W = (mat < 2) ? (Wt + (size_t)mat * IN_DIM * OUT_DIM) : Wres;

    int tid = threadIdx.x;
    int tr = tid >> 4;   // 0..15: 4-row group
    int tc = tid & 15;   // 0..15: 4-col group

    float acc[4][4] = {};
    for (int kt = 0; kt < IN_DIM; kt += TK) {
        for (int l = tid; l < TM * (TK / 4); l += 256) {
            int n = l >> 3;
            int k4 = (l & 7) << 2;
            int gn = n0 + n;
            float4 v = make_float4(0.f, 0.f, 0.f, 0.f);
            if (gn < N_NODES)
                v = *(const float4*)(x + (size_t)gn * IN_DIM + kt + k4);
            As[k4 + 0][n] = v.x;
            As[k4 + 1][n] = v.y;
            As[k4 + 2][n] = v.z;
            As[k4 + 3][n] = v.w;
        }
        for (int l = tid; l < TK * (OUT_DIM / 4); l += 256) {
            int kk = l >> 4;
            int c4 = (l & 15) << 2;
            *(float4*)&Bs[kk][c4] =
                *(const float4*)(W + (size_t)(kt + kk) * OUT_DIM + c4);
        }
        __syncthreads();
#pragma unroll
        for (int kk = 0; kk < TK; ++kk) {
            float4 a4 = *(const float4*)&As[kk][tr * 4];
            float4 b4 = *(const float4*)&Bs[kk][tc * 4];
            float av[4] = {a4.x, a4.y, a4.z, a4.w};
            float bv[4] = {b4.x, b4.y, b4.z, b4.w};
#pragma unroll
            for (int i = 0; i < 4; ++i)
#pragma unroll
                for (int j = 0; j < 4; ++j)
                    acc[i][j] = fmaf(av[i], bv[j], acc[i][j]);
        }
        __syncthreads();
    }

    if (mat < 2) {
        // bf16 wx write (8B per row-fragment)
        size_t base = (size_t)mat * N_NODES * OUT_DIM;
#pragma unroll
        for (int i = 0; i < 4; ++i) {
            int gn = n0 + tr * 4 + i;
            if (gn < N_NODES) {
                unsigned lo = (unsigned)f2bf(acc[i][0]) | ((unsigned)f2bf(acc[i][1]) << 16);
                unsigned hi = (unsigned)f2bf(acc[i][2]) | ((unsigned)f2bf(acc[i][3]) << 16);
                uint2 pv; pv.x = lo; pv.y = hi;
                *(uint2*)&wxh[base + (size_t)gn * OUT_DIM + tc * 4] = pv;
            }
        }
        // al/ar epilogue: 16-lane (tc-group) shfl reduction
        const float* wlk = wl + mat * 3 * OUT_DIM;
        const float* wrk = wr + mat * 3 * OUT_DIM;
#pragma unroll
        for (int s = 0; s < 3; ++s) {
            float wls[4], wrs[4];
#pragma unroll
            for (int j = 0; j < 4; ++j) {
                wls[j] = wlk[s * OUT_DIM + tc * 4 + j];
                wrs[j] = wrk[s * OUT_DIM + tc * 4 + j];
            }
#pragma unroll
            for (int i = 0; i < 4; ++i) {
                float pl = 0.f, pr = 0.f;
#pragma unroll
                for (int j = 0; j < 4; ++j) {
                    pl = fmaf(acc[i][j], wls[j], pl);
                    pr = fmaf(acc[i][j], wrs[j], pr);
                }
#pragma unroll
                for (int off = 1; off < 16; off <<= 1) {
                    pl += __shfl_xor(pl, off);
                    pr += __shfl_xor(pr, off);
                }
                if (tc == 0) {
                    int gn = n0 + tr * 4 + i;
                    if (gn < N_NODES) {
                        al[(size_t)gn * 6 + mat * 3 + s] = pl;
                        ar[(size_t)gn * 6 + mat * 3 + s] = pr;
                    }
                }
            }
        }
    } else {
#pragma unroll
        for (int i = 0; i < 4; ++i) {
            int gn = n0 + tr * 4 + i;
            if (gn < N_NODES)
                *(float4*)(xres + (size_t)gn * OUT_DIM + tc * 4) =
                    make_float4(acc[i][0], acc[i][1], acc[i][2], acc[i][3]);
        }
    }
}

// ---------------------------------------------------------------------------
// CSR build: histogram -> 3-phase parallel scan
// ---------------------------------------------------------------------------
__global__ void hist_kernel(const int* __restrict__ rows, int* __restrict__ deg) {
    int e = blockIdx.x * 256 + threadIdx.x;
    if (e >= N_EDGES) return;
    atomicAdd(&deg[rows[e]], 1);
}

__global__ void scan1_kernel(const int* __restrict__ deg, int* __restrict__ bsum) {
    __shared__ int sh[256];
    int t = threadIdx.x;
    int i = blockIdx.x * 256 + t;
    sh[t] = (i < N_NODES) ? deg[i] : 0;
    __syncthreads();
    for (int off = 128; off > 0; off >>= 1) {
        if (t < off) sh[t] += sh[t + off];
        __syncthreads();
    }
    if (t == 0) bsum[blockIdx.x] = sh[0];
}

__global__ void scan2_kernel(int* __restrict__ bsum, int* __restrict__ row_ptr) {
    __shared__ int sh[256];
    int t = threadIdx.x;
    sh[t] = (t < NB_SCAN) ? bsum[t] : 0;
    __syncthreads();
    if (t == 0) {
        int a = 0;
        for (int i = 0; i < NB_SCAN; ++i) { int v = sh[i]; sh[i] = a; a += v; }
        row_ptr[N_NODES] = N_EDGES;
    }
    __syncthreads();
    if (t < NB_SCAN) bsum[t] = sh[t];
}

__global__ void scan3_kernel(const int* __restrict__ deg,
                             const int* __restrict__ bpre,
                             int* __restrict__ row_ptr,
                             int* __restrict__ cursor) {
    __shared__ int sh[256];
    int t = threadIdx.x;
    int i = blockIdx.x * 256 + t;
    int v = (i < N_NODES) ? deg[i] : 0;
    sh[t] = v;
    int val = v;
    __syncthreads();
    for (int off = 1; off < 256; off <<= 1) {
        int y = (t >= off) ? sh[t - off] : 0;
        __syncthreads();
        val += y;
        sh[t] = val;
        __syncthreads();
    }
    if (i < N_NODES) {
        int rp = bpre[blockIdx.x] + val - v;   // exclusive prefix
        row_ptr[i] = rp;
        cursor[i] = rp;
    }
}

// ---------------------------------------------------------------------------
// Scatter with fused score computation: per edge, compute scores for both k
// (atten/support read coalesced by edge id; al/ar gathers are L2-resident),
// scatter {col, s0, s1} into CSR slots.
// ---------------------------------------------------------------------------
__global__ void scatter_score_kernel(const int* __restrict__ rows,
                                     const int* __restrict__ cols,
                                     const float* __restrict__ atten,
                                     const float* __restrict__ support,
                                     const float* __restrict__ al,
                                     const float* __restrict__ ar,
                                     int* __restrict__ cursor,
                                     int* __restrict__ cols_s,
                                     float* __restrict__ s0,
                                     float* __restrict__ s1) {
    int e = blockIdx.x * 256 + threadIdx.x;
    if (e >= N_EDGES) return;
    int r = rows[e], c = cols[e];
    float a0  = atten[e];
    float a1  = atten[N_EDGES + e];
    float sp0 = support[e];
    float sp1 = support[N_EDGES + e];
    const float* alr = al + (size_t)r * 6;
    const float* arc = ar + (size_t)c * 6;
    float sc0 = (alr[0] + arc[0]) * a0 + (alr[1] + arc[1]) * a1 + (alr[2] + arc[2]) * sp0;
    float sc1 = (alr[3] + arc[3]) * a0 + (alr[4] + arc[4]) * a1 + (alr[5] + arc[5]) * sp1;
    int pos = atomicAdd(&cursor[r], 1);
    cols_s[pos] = c;
    s0[pos] = sc0;
    s1[pos] = sc1;
}

// ---------------------------------------------------------------------------
// Fused softmax + SpMM + residual + elu: one wave per row.
// ---------------------------------------------------------------------------
__global__ void attn_kernel(const int* __restrict__ row_ptr,
                            const int* __restrict__ cols_s,
                            const float* __restrict__ s0,
                            const float* __restrict__ s1,
                            const ushort_t* __restrict__ wxh,
                            const float* __restrict__ xres,
                            const float* __restrict__ Wres,
                            float* __restrict__ out) {
    int wid = blockIdx.x * 4 + (threadIdx.x >> 6);
    if (wid >= N_NODES) return;
    int lane = threadIdx.x & 63;
    int beg = row_ptr[wid], end = row_ptr[wid + 1];
    int deg = end - beg;
    const ushort_t* w0 = wxh;
    const ushort_t* w1 = wxh + (size_t)N_NODES * OUT_DIM;
    float a = 0.f;

    if (deg > 0 && deg <= 64) {
        int pos = beg + lane;
        bool valid = lane < deg;
        int c = valid ? cols_s[pos] : 0;
        float sc0 = valid ? s0[pos] : NEG_INF;
        float sc1 = valid ? s1[pos] : NEG_INF;
        float m0 = sc0, m1 = sc1;
#pragma unroll
        for (int off = 32; off > 0; off >>= 1) {
            m0 = fmaxf(m0, __shfl_xor(m0, off));
            m1 = fmaxf(m1, __shfl_xor(m1, off));
        }
        float e0 = valid ? __expf(sc0 - m0) : 0.f;
        float e1 = valid ? __expf(sc1 - m1) : 0.f;
        float l0 = e0, l1 = e1;
#pragma unroll
        for (int off = 32; off > 0; off >>= 1) {
            l0 += __shfl_xor(l0, off);
            l1 += __shfl_xor(l1, off);
        }
        float p0 = e0 / l0;
        float p1 = e1 / l1;
        int i = 0;
        for (; i + 4 <= deg; i += 4) {
            int c0 = __shfl(c, i),     c1 = __shfl(c, i + 1);
            int c2 = __shfl(c, i + 2), c3 = __shfl(c, i + 3);
            float q00 = __shfl(p0, i),     q01 = __shfl(p0, i + 1);
            float q02 = __shfl(p0, i + 2), q03 = __shfl(p0, i + 3);
            float q10 = __shfl(p1, i),     q11 = __shfl(p1, i + 1);
            float q12 = __shfl(p1, i + 2), q13 = __shfl(p1, i + 3);
            float v00 = bf2f(w0[(size_t)c0 * OUT_DIM + lane]);
            float v01 = bf2f(w0[(size_t)c1 * OUT_DIM + lane]);
            float v02 = bf2f(w0[(size_t)c2 * OUT_DIM + lane]);
            float v03 = bf2f(w0[(size_t)c3 * OUT_DIM + lane]);
            float v10 = bf2f(w1[(size_t)c0 * OUT_DIM + lane]);
            float v11 = bf2f(w1[(size_t)c1 * OUT_DIM + lane]);
            float v12 = bf2f(w1[(size_t)c2 * OUT_DIM + lane]);
            float v13 = bf2f(w1[(size_t)c3 * OUT_DIM + lane]);
            a = fmaf(q00, v00, a); a = fmaf(q01, v01, a);
            a = fmaf(q02, v02, a); a = fmaf(q03, v03, a);
            a = fmaf(q10, v10, a); a = fmaf(q11, v11, a);
            a = fmaf(q12, v12, a); a = fmaf(q13, v13, a);
        }
        for (; i < deg; ++i) {
            int ci = __shfl(c, i);
            float q0 = __shfl(p0, i), q1 = __shfl(p1, i);
            a = fmaf(q0, bf2f(w0[(size_t)ci * OUT_DIM + lane]), a);
            a = fmaf(q1, bf2f(w1[(size_t)ci * OUT_DIM + lane]), a);
        }
    } else if (deg > 64) {
        // rare long-row path: online softmax, then chunked spmm
        float m0 = NEG_INF, l0 = 0.f, m1 = NEG_INF, l1 = 0.f;
        for (int base = beg; base < end; base += 64) {
            int pos = base + lane;
            bool valid = pos < end;
            float sc0 = valid ? s0[pos] : NEG_INF;
            float sc1 = valid ? s1[pos] : NEG_INF;
            float cm0 = sc0, cm1 = sc1;
#pragma unroll
            for (int off = 32; off > 0; off >>= 1) {
                cm0 = fmaxf(cm0, __shfl_xor(cm0, off));
                cm1 = fmaxf(cm1, __shfl_xor(cm1, off));
            }
            float mn0 = fmaxf(m0, cm0), mn1 = fmaxf(m1, cm1);
            float e0 = valid ? __expf(sc0 - mn0) : 0.f;
            float e1 = valid ? __expf(sc1 - mn1) : 0.f;
#pragma unroll
            for (int off = 32; off > 0; off >>= 1) {
                e0 += __shfl_xor(e0, off);
                e1 += __shfl_xor(e1, off);
            }
            l0 = l0 * __expf(m0 - mn0) + e0;
            l1 = l1 * __expf(m1 - mn1) + e1;
            m0 = mn0; m1 = mn1;
        }
        float inv0 = 1.f / l0, inv1 = 1.f / l1;
        for (int base = beg; base < end; base += 64) {
            int pos = base + lane;
            bool valid = pos < end;
            int c = valid ? cols_s[pos] : 0;
            float p0 = valid ? __expf(s0[pos] - m0) * inv0 : 0.f;
            float p1 = valid ? __expf(s1[pos] - m1) * inv1 : 0.f;
            int cnt = min(64, end - base);
            for (int i = 0; i < cnt; ++i) {
                int ci = __shfl(c, i);
                float q0 = __shfl(p0, i), q1 = __shfl(p1, i);
                a = fmaf(q0, bf2f(w0[(size_t)ci * OUT_DIM + lane]), a);
                a = fmaf(q1, bf2f(w1[(size_t)ci * OUT_DIM + lane]), a);
            }
        }
    }

    // residual: out = elu(xres + acc @ Wres[128:])
    const float* Wres2 = Wres + (size_t)IN_DIM * OUT_DIM;
    float r = xres[(size_t)wid * OUT_DIM + lane];
#pragma unroll 8
    for (int d = 0; d < OUT_DIM; ++d) {
        float ad = __shfl(a, d);
        r = fmaf(ad, Wres2[d * OUT_DIM + lane], r);
    }
    out[(size_t)wid * OUT_DIM + lane] = (r > 0.f) ? r : expm1f(r);
}

extern "C" void kernel_launch(void* const* d_in, const int* in_sizes, int n_in,
                              void* d_out, int out_size, void* d_ws, size_t ws_size,
                              hipStream_t stream) {
    const float* x       = (const float*)d_in[0];
    const float* support = (const float*)d_in[1];
    const float* atten   = (const float*)d_in[2];
    const float* Wt      = (const float*)d_in[3];
    const float* wl      = (const float*)d_in[4];
    const float* wr      = (const float*)d_in[5];
    const float* Wres    = (const float*)d_in[6];
    const int*   rows    = (const int*)d_in[7];
    const int*   cols    = (const int*)d_in[8];
    float* out = (float*)d_out;

    // workspace layout
    ushort_t* wxh  = (ushort_t*)d_ws;                                  // K*N*64 bf16
    float* xres    = (float*)(wxh + (size_t)K_KERNELS * N_NODES * OUT_DIM); // N*64
    float* al      = xres + (size_t)N_NODES * OUT_DIM;                 // N*6
    float* ar      = al + (size_t)N_NODES * 6;                         // N*6
    float* s0      = ar + (size_t)N_NODES * 6;                         // E
    float* s1      = s0 + (size_t)N_EDGES;                             // E
    int*   cols_s  = (int*)(s1 + (size_t)N_EDGES);                     // E
    int*   deg     = cols_s + N_EDGES;                                 // N
    int*   row_ptr = deg + N_NODES;                                    // N+1
    int*   cursor  = row_ptr + N_NODES + 1;                            // N
    int*   bsum    = cursor + N_NODES;                                 // NB_SCAN

    hipMemsetAsync(deg, 0, (size_t)N_NODES * sizeof(int), stream);

    gemm_kernel<<<3 * NBLK, 256, 0, stream>>>(x, Wt, Wres, wl, wr, wxh, xres, al, ar);
    hist_kernel<<<(N_EDGES + 255) / 256, 256, 0, stream>>>(rows, deg);
    scan1_kernel<<<NB_SCAN, 256, 0, stream>>>(deg, bsum);
    scan2_kernel<<<1, 256, 0, stream>>>(bsum, row_ptr);
    scan3_kernel<<<NB_SCAN, 256, 0, stream>>>(deg, bsum, row_ptr, cursor);
    scatter_score_kernel<<<(N_EDGES + 255) / 256, 256, 0, stream>>>(
        rows, cols, atten, support, al, ar, cursor, cols_s, s0, s1);
    attn_kernel<<<(N_NODES + 3) / 4, 256, 0, stream>>>(
        row_ptr, cols_s, s0, s1, wxh, xres, Wres, out);
}

// Round 5
// 188.814 us; speedup vs baseline: 4.4845x; 1.2132x over previous
//
#include <hip/hip_runtime.h>

#define N_NODES 50000
#define N_EDGES 800000
#define IN_DIM 128
#define OUT_DIM 64
#define K_KERNELS 2
#define NEG_INF (-1e30f)
#define TM 64
#define TK 32
#define NBLK ((N_NODES + TM - 1) / TM)       // 782
#define NB_SCAN ((N_NODES + 255) / 256)      // 196

typedef unsigned short ushort_t;

__device__ __forceinline__ unsigned f2bf(float f) {
    unsigned u = __float_as_uint(f);
    u += 0x7fffu + ((u >> 16) & 1u);         // round-to-nearest-even
    return u >> 16;
}
__device__ __forceinline__ unsigned rl_u(unsigned v, int i) {
    return __builtin_amdgcn_readlane(v, i);
}
__device__ __forceinline__ float rl_f(float v, int i) {
    return __uint_as_float(__builtin_amdgcn_readlane(__float_as_uint(v), i));
}

// ---------------------------------------------------------------------------
// Tiled f32 GEMM, all 3 weight mats per block (shared x tile).
// mats 0,1 -> wxi packed {bf16 k0, bf16 k1} + al/ar epilogue; mat 2 -> xres.
// ---------------------------------------------------------------------------
__global__ __launch_bounds__(256) void gemm_kernel(
        const float* __restrict__ x,
        const float* __restrict__ Wt,
        const float* __restrict__ Wres,
        const float* __restrict__ wl,
        const float* __restrict__ wr,
        unsigned* __restrict__ wxi,
        float* __restrict__ xres,
        float* __restrict__ al,
        float* __restrict__ ar) {
    __shared__ float As[TK][TM];          // x tile transposed
    __shared__ float Bs[3][TK][OUT_DIM];  // 3 weight tiles
    int n0 = blockIdx.x * TM;
    int tid = threadIdx.x;
    int tr = tid >> 4;   // 0..15 row group
    int tc = tid & 15;   // 0..15 col group

    float acc[3][4][4] = {};
    for (int kt = 0; kt < IN_DIM; kt += TK) {
        for (int l = tid; l < TM * (TK / 4); l += 256) {
            int n = l >> 3;
            int k4 = (l & 7) << 2;
            int gn = n0 + n;
            float4 v = make_float4(0.f, 0.f, 0.f, 0.f);
            if (gn < N_NODES)
                v = *(const float4*)(x + (size_t)gn * IN_DIM + kt + k4);
            As[k4 + 0][n] = v.x;
            As[k4 + 1][n] = v.y;
            As[k4 + 2][n] = v.z;
            As[k4 + 3][n] = v.w;
        }
        for (int l = tid; l < 3 * TK * (OUT_DIM / 4); l += 256) {
            int mat = l >> 9;
            int rem = l & 511;
            int kk = rem >> 4;
            int c4 = (rem & 15) << 2;
            const float* W = (mat == 0) ? Wt
                           : (mat == 1) ? (Wt + (size_t)IN_DIM * OUT_DIM)
                                        : Wres;
            *(float4*)&Bs[mat][kk][c4] =
                *(const float4*)(W + (size_t)(kt + kk) * OUT_DIM + c4);
        }
        __syncthreads();
#pragma unroll
        for (int kk = 0; kk < TK; ++kk) {
            float4 a4 = *(const float4*)&As[kk][tr * 4];
            float av[4] = {a4.x, a4.y, a4.z, a4.w};
#pragma unroll
            for (int mat = 0; mat < 3; ++mat) {
                float4 b4 = *(const float4*)&Bs[mat][kk][tc * 4];
                float bv[4] = {b4.x, b4.y, b4.z, b4.w};
#pragma unroll
                for (int i = 0; i < 4; ++i)
#pragma unroll
                    for (int j = 0; j < 4; ++j)
                        acc[mat][i][j] = fmaf(av[i], bv[j], acc[mat][i][j]);
            }
        }
        __syncthreads();
    }

    // packed wx + xres writes
#pragma unroll
    for (int i = 0; i < 4; ++i) {
        int gn = n0 + tr * 4 + i;
        if (gn < N_NODES) {
            uint4 pv;
            pv.x = f2bf(acc[0][i][0]) | (f2bf(acc[1][i][0]) << 16);
            pv.y = f2bf(acc[0][i][1]) | (f2bf(acc[1][i][1]) << 16);
            pv.z = f2bf(acc[0][i][2]) | (f2bf(acc[1][i][2]) << 16);
            pv.w = f2bf(acc[0][i][3]) | (f2bf(acc[1][i][3]) << 16);
            *(uint4*)&wxi[(size_t)gn * OUT_DIM + tc * 4] = pv;
            *(float4*)(xres + (size_t)gn * OUT_DIM + tc * 4) =
                make_float4(acc[2][i][0], acc[2][i][1], acc[2][i][2], acc[2][i][3]);
        }
    }
    // al/ar epilogue: 16-lane shfl reductions
#pragma unroll
    for (int mat = 0; mat < 2; ++mat) {
        const float* wlk = wl + mat * 3 * OUT_DIM;
        const float* wrk = wr + mat * 3 * OUT_DIM;
#pragma unroll
        for (int s = 0; s < 3; ++s) {
            float wls[4], wrs[4];
#pragma unroll
            for (int j = 0; j < 4; ++j) {
                wls[j] = wlk[s * OUT_DIM + tc * 4 + j];
                wrs[j] = wrk[s * OUT_DIM + tc * 4 + j];
            }
#pragma unroll
            for (int i = 0; i < 4; ++i) {
                float pl = 0.f, pr = 0.f;
#pragma unroll
                for (int j = 0; j < 4; ++j) {
                    pl = fmaf(acc[mat][i][j], wls[j], pl);
                    pr = fmaf(acc[mat][i][j], wrs[j], pr);
                }
#pragma unroll
                for (int off = 1; off < 16; off <<= 1) {
                    pl += __shfl_xor(pl, off);
                    pr += __shfl_xor(pr, off);
                }
                if (tc == 0) {
                    int gn = n0 + tr * 4 + i;
                    if (gn < N_NODES) {
                        al[(size_t)gn * 6 + mat * 3 + s] = pl;
                        ar[(size_t)gn * 6 + mat * 3 + s] = pr;
                    }
                }
            }
        }
    }
}

// ---------------------------------------------------------------------------
// CSR build
// ---------------------------------------------------------------------------
__global__ void hist_kernel(const int* __restrict__ rows, int* __restrict__ deg) {
    int e = blockIdx.x * 256 + threadIdx.x;
    if (e >= N_EDGES) return;
    atomicAdd(&deg[rows[e]], 1);
}

__global__ void scan1_kernel(const int* __restrict__ deg, int* __restrict__ bsum) {
    __shared__ int sh[256];
    int t = threadIdx.x;
    int i = blockIdx.x * 256 + t;
    sh[t] = (i < N_NODES) ? deg[i] : 0;
    __syncthreads();
    for (int off = 128; off > 0; off >>= 1) {
        if (t < off) sh[t] += sh[t + off];
        __syncthreads();
    }
    if (t == 0) bsum[blockIdx.x] = sh[0];
}

// fused: block-prefix over bsum + intra-block Hillis-Steele scan
__global__ void scan3_kernel(const int* __restrict__ deg,
                             const int* __restrict__ bsum,
                             int* __restrict__ row_ptr,
                             int* __restrict__ cursor) {
    __shared__ int pref[256];
    __shared__ int sh[256];
    int t = threadIdx.x;
    pref[t] = (t < (int)blockIdx.x && t < NB_SCAN) ? bsum[t] : 0;
    __syncthreads();
    for (int off = 128; off > 0; off >>= 1) {
        if (t < off) pref[t] += pref[t + off];
        __syncthreads();
    }
    int bpre = pref[0];
    int i = blockIdx.x * 256 + t;
    int v = (i < N_NODES) ? deg[i] : 0;
    sh[t] = v;
    int val = v;
    __syncthreads();
    for (int off = 1; off < 256; off <<= 1) {
        int y = (t >= off) ? sh[t - off] : 0;
        __syncthreads();
        val += y;
        sh[t] = val;
        __syncthreads();
    }
    if (i < N_NODES) {
        int rp = bpre + val - v;   // exclusive prefix
        row_ptr[i] = rp;
        cursor[i] = rp;
    }
    if (blockIdx.x == 0 && t == 0) row_ptr[N_NODES] = N_EDGES;
}

// ---------------------------------------------------------------------------
// Scatter + fused score: one 16B packed record {col, s0, s1, 0} per edge.
// ---------------------------------------------------------------------------
__global__ void scatter_score_kernel(const int* __restrict__ rows,
                                     const int* __restrict__ cols,
                                     const float* __restrict__ atten,
                                     const float* __restrict__ support,
                                     const float* __restrict__ al,
                                     const float* __restrict__ ar,
                                     int* __restrict__ cursor,
                                     uint4* __restrict__ edata) {
    int e = blockIdx.x * 256 + threadIdx.x;
    if (e >= N_EDGES) return;
    int r = rows[e], c = cols[e];
    float a0  = atten[e];
    float a1  = atten[N_EDGES + e];
    float sp0 = support[e];
    float sp1 = support[N_EDGES + e];
    const float* alr = al + (size_t)r * 6;
    const float* arc = ar + (size_t)c * 6;
    float sc0 = (alr[0] + arc[0]) * a0 + (alr[1] + arc[1]) * a1 + (alr[2] + arc[2]) * sp0;
    float sc1 = (alr[3] + arc[3]) * a0 + (alr[4] + arc[4]) * a1 + (alr[5] + arc[5]) * sp1;
    int pos = atomicAdd(&cursor[r], 1);
    uint4 pv;
    pv.x = (unsigned)c;
    pv.y = __float_as_uint(sc0);
    pv.z = __float_as_uint(sc1);
    pv.w = 0u;
    edata[pos] = pv;
}

// ---------------------------------------------------------------------------
// Fused softmax + SpMM + residual + elu: one wave per row.
// Packed wxi gather (1 dword/lane/edge), readlane broadcasts, 4 accumulators.
// ---------------------------------------------------------------------------
__global__ void attn_kernel(const int* __restrict__ row_ptr,
                            const uint4* __restrict__ edata,
                            const unsigned* __restrict__ wxi,
                            const float* __restrict__ xres,
                            const float* __restrict__ Wres,
                            float* __restrict__ out) {
    int wid = blockIdx.x * 4 + (threadIdx.x >> 6);
    if (wid >= N_NODES) return;
    int lane = threadIdx.x & 63;
    int beg = row_ptr[wid], end = row_ptr[wid + 1];
    int deg = end - beg;
    float a = 0.f;

    if (deg > 0 && deg <= 64) {
        bool valid = lane < deg;
        uint4 ed = edata[valid ? beg + lane : beg];
        unsigned c = ed.x;
        float sc0 = valid ? __uint_as_float(ed.y) : NEG_INF;
        float sc1 = valid ? __uint_as_float(ed.z) : NEG_INF;
        float m0 = sc0, m1 = sc1;
#pragma unroll
        for (int off = 32; off > 0; off >>= 1) {
            m0 = fmaxf(m0, __shfl_xor(m0, off));
            m1 = fmaxf(m1, __shfl_xor(m1, off));
        }
        float e0 = valid ? __expf(sc0 - m0) : 0.f;
        float e1 = valid ? __expf(sc1 - m1) : 0.f;
        float l0 = e0, l1 = e1;
#pragma unroll
        for (int off = 32; off > 0; off >>= 1) {
            l0 += __shfl_xor(l0, off);
            l1 += __shfl_xor(l1, off);
        }
        float p0 = e0 / l0;
        float p1 = e1 / l1;
        float a0 = 0.f, a1 = 0.f, a2 = 0.f, a3 = 0.f;
        int i = 0;
        for (; i + 4 <= deg; i += 4) {
            unsigned c0 = rl_u(c, i),     c1 = rl_u(c, i + 1);
            unsigned c2 = rl_u(c, i + 2), c3 = rl_u(c, i + 3);
            unsigned v0 = wxi[(size_t)c0 * OUT_DIM + lane];
            unsigned v1 = wxi[(size_t)c1 * OUT_DIM + lane];
            unsigned v2 = wxi[(size_t)c2 * OUT_DIM + lane];
            unsigned v3 = wxi[(size_t)c3 * OUT_DIM + lane];
            a0 = fmaf(rl_f(p0, i),     __uint_as_float(v0 << 16), a0);
            a0 = fmaf(rl_f(p1, i),     __uint_as_float(v0 & 0xffff0000u), a0);
            a1 = fmaf(rl_f(p0, i + 1), __uint_as_float(v1 << 16), a1);
            a1 = fmaf(rl_f(p1, i + 1), __uint_as_float(v1 & 0xffff0000u), a1);
            a2 = fmaf(rl_f(p0, i + 2), __uint_as_float(v2 << 16), a2);
            a2 = fmaf(rl_f(p1, i + 2), __uint_as_float(v2 & 0xffff0000u), a2);
            a3 = fmaf(rl_f(p0, i + 3), __uint_as_float(v3 << 16), a3);
            a3 = fmaf(rl_f(p1, i + 3), __uint_as_float(v3 & 0xffff0000u), a3);
        }
        for (; i < deg; ++i) {
            unsigned ci = rl_u(c, i);
            unsigned v = wxi[(size_t)ci * OUT_DIM + lane];
            a0 = fmaf(rl_f(p0, i), __uint_as_float(v << 16), a0);
            a0 = fmaf(rl_f(p1, i), __uint_as_float(v & 0xffff0000u), a0);
        }
        a = (a0 + a1) + (a2 + a3);
    } else if (deg > 64) {
        // rare long-row path: online softmax, then chunked spmm
        float m0 = NEG_INF, l0 = 0.f, m1 = NEG_INF, l1 = 0.f;
        for (int base = beg; base < end; base += 64) {
            int pos = base + lane;
            bool valid = pos < end;
            uint4 ed = edata[valid ? pos : beg];
            float sc0 = valid ? __uint_as_float(ed.y) : NEG_INF;
            float sc1 = valid ? __uint_as_float(ed.z) : NEG_INF;
            float cm0 = sc0, cm1 = sc1;
#pragma unroll
            for (int off = 32; off > 0; off >>= 1) {
                cm0 = fmaxf(cm0, __shfl_xor(cm0, off));
                cm1 = fmaxf(cm1, __shfl_xor(cm1, off));
            }
            float mn0 = fmaxf(m0, cm0), mn1 = fmaxf(m1, cm1);
            float e0 = valid ? __expf(sc0 - mn0) : 0.f;
            float e1 = valid ? __expf(sc1 - mn1) : 0.f;
#pragma unroll
            for (int off = 32; off > 0; off >>= 1) {
                e0 += __shfl_xor(e0, off);
                e1 += __shfl_xor(e1, off);
            }
            l0 = l0 * __expf(m0 - mn0) + e0;
            l1 = l1 * __expf(m1 - mn1) + e1;
            m0 = mn0; m1 = mn1;
        }
        float inv0 = 1.f / l0, inv1 = 1.f / l1;
        for (int base = beg; base < end; base += 64) {
            int pos = base + lane;
            bool valid = pos < end;
            uint4 ed = edata[valid ? pos : beg];
            unsigned c = ed.x;
            float p0 = valid ? __expf(__uint_as_float(ed.y) - m0) * inv0 : 0.f;
            float p1 = valid ? __expf(__uint_as_float(ed.z) - m1) * inv1 : 0.f;
            int cnt = min(64, end - base);
            for (int i = 0; i < cnt; ++i) {
                unsigned ci = rl_u(c, i);
                unsigned v = wxi[(size_t)ci * OUT_DIM + lane];
                a = fmaf(rl_f(p0, i), __uint_as_float(v << 16), a);
                a = fmaf(rl_f(p1, i), __uint_as_float(v & 0xffff0000u), a);
            }
        }
    }

    // residual: out = elu(xres + acc @ Wres[128:]) ; readlane broadcasts
    const float* Wres2 = Wres + (size_t)IN_DIM * OUT_DIM;
    float r = xres[(size_t)wid * OUT_DIM + lane];
#pragma unroll
    for (int d = 0; d < OUT_DIM; ++d) {
        float ad = rl_f(a, d);
        r = fmaf(ad, Wres2[d * OUT_DIM + lane], r);
    }
    out[(size_t)wid * OUT_DIM + lane] = (r > 0.f) ? r : expm1f(r);
}

extern "C" void kernel_launch(void* const* d_in, const int* in_sizes, int n_in,
                              void* d_out, int out_size, void* d_ws, size_t ws_size,
                              hipStream_t stream) {
    const float* x       = (const float*)d_in[0];
    const float* support = (const float*)d_in[1];
    const float* atten   = (const float*)d_in[2];
    const float* Wt      = (const float*)d_in[3];
    const float* wl      = (const float*)d_in[4];
    const float* wr      = (const float*)d_in[5];
    const float* Wres    = (const float*)d_in[6];
    const int*   rows    = (const int*)d_in[7];
    const int*   cols    = (const int*)d_in[8];
    float* out = (float*)d_out;

    // workspace layout (16B-aligned sections)
    unsigned* wxi  = (unsigned*)d_ws;                                  // N*64 packed
    float* xres    = (float*)(wxi + (size_t)N_NODES * OUT_DIM);        // N*64
    float* al      = xres + (size_t)N_NODES * OUT_DIM;                 // N*6
    float* ar      = al + (size_t)N_NODES * 6;                         // N*6
    uint4* edata   = (uint4*)(ar + (size_t)N_NODES * 6);               // E * 16B
    int*   deg     = (int*)(edata + (size_t)N_EDGES);                  // N
    int*   row_ptr = deg + N_NODES;                                    // N+1
    int*   cursor  = row_ptr + N_NODES + 1;                            // N
    int*   bsum    = cursor + N_NODES;                                 // NB_SCAN

    hipMemsetAsync(deg, 0, (size_t)N_NODES * sizeof(int), stream);

    gemm_kernel<<<NBLK, 256, 0, stream>>>(x, Wt, Wres, wl, wr, wxi, xres, al, ar);
    hist_kernel<<<(N_EDGES + 255) / 256, 256, 0, stream>>>(rows, deg);
    scan1_kernel<<<NB_SCAN, 256, 0, stream>>>(deg, bsum);
    scan3_kernel<<<NB_SCAN, 256, 0, stream>>>(deg, bsum, row_ptr, cursor);
    scatter_score_kernel<<<(N_EDGES + 255) / 256, 256, 0, stream>>>(
        rows, cols, atten, support, al, ar, cursor, edata);
    attn_kernel<<<(N_NODES + 3) / 4, 256, 0, stream>>>(
        row_ptr, edata, wxi, xres, Wres, out);
}

// Round 6
// 166.920 us; speedup vs baseline: 5.0727x; 1.1312x over previous
//
#include <hip/hip_runtime.h>

#define N_NODES 50000
#define N_EDGES 800000
#define IN_DIM 128
#define OUT_DIM 64
#define NEG_INF (-1e30f)
#define NB_SCAN ((N_NODES + 255) / 256)      // 196
#define GBLK ((N_NODES + 63) / 64)           // 782

typedef unsigned short ushort_t;
typedef __attribute__((ext_vector_type(8))) short short8;
typedef __attribute__((ext_vector_type(4))) float f32x4;

__device__ __forceinline__ unsigned f2bf(float f) {
    unsigned u = __float_as_uint(f);
    u += 0x7fffu + ((u >> 16) & 1u);         // round-to-nearest-even
    return u >> 16;
}
__device__ __forceinline__ unsigned rl_u(unsigned v, int i) {
    return __builtin_amdgcn_readlane(v, i);
}
__device__ __forceinline__ float rl_f(float v, int i) {
    return __uint_as_float(__builtin_amdgcn_readlane(__float_as_uint(v), i));
}

// ---------------------------------------------------------------------------
// Pack the 3 weight matrices (Wt[0], Wt[1], Wres[:128]) into MFMA B-fragment
// order, bf16. Frag f = (mat*4+ct)*4+kc; within frag: [lane][b] where
// B[k][c], k = kc*32 + (lane>>4)*8 + b, c = ct*16 + (lane&15).
// ---------------------------------------------------------------------------
__global__ void wpack_kernel(const float* __restrict__ Wt,
                             const float* __restrict__ Wres,
                             ushort_t* __restrict__ Wpack) {
    int idx = blockIdx.x * 256 + threadIdx.x;   // 0 .. 3*16*512-1 = 24575
    if (idx >= 3 * 16 * 512) return;
    int f = idx >> 9;          // frag id
    int within = idx & 511;
    int lane = within >> 3;
    int b = within & 7;
    int mat = f >> 4;
    int ct = (f >> 2) & 3;
    int kc = f & 3;
    int k = kc * 32 + (lane >> 4) * 8 + b;
    int c = ct * 16 + (lane & 15);
    const float* W = (mat < 2) ? (Wt + (size_t)mat * IN_DIM * OUT_DIM) : Wres;
    Wpack[idx] = (ushort_t)f2bf(W[(size_t)k * OUT_DIM + c]);
}

// ---------------------------------------------------------------------------
// MFMA GEMM: per block 64 rows; per wave 16 rows x 64 cols x 3 mats.
// No LDS, no barriers. mats 0,1 -> wxi packed bf16 pair + al/ar epilogue;
// mat 2 -> xres f32.
// ---------------------------------------------------------------------------
__global__ __launch_bounds__(256) void gemm_kernel(
        const float* __restrict__ x,
        const ushort_t* __restrict__ Wpack,
        const float* __restrict__ wl,
        const float* __restrict__ wr,
        unsigned* __restrict__ wxi,
        float* __restrict__ xres,
        float* __restrict__ al,
        float* __restrict__ ar) {
    int wave = threadIdx.x >> 6;
    int lane = threadIdx.x & 63;
    int lr = lane & 15;        // row (A) / col (B,C)
    int lg = lane >> 4;        // k-group / C row-group
    int row0 = blockIdx.x * 64 + wave * 16;

    // A fragments: x[row0+lr][kc*32 + lg*8 + 0..7] -> bf16
    int arow = row0 + lr;
    if (arow >= N_NODES) arow = N_NODES - 1;
    const float* xr = x + (size_t)arow * IN_DIM;
    short8 afrag[4];
#pragma unroll
    for (int kc = 0; kc < 4; ++kc) {
        float4 f0 = *(const float4*)(xr + kc * 32 + lg * 8);
        float4 f1 = *(const float4*)(xr + kc * 32 + lg * 8 + 4);
        short8 a;
        a[0] = (short)f2bf(f0.x); a[1] = (short)f2bf(f0.y);
        a[2] = (short)f2bf(f0.z); a[3] = (short)f2bf(f0.w);
        a[4] = (short)f2bf(f1.x); a[5] = (short)f2bf(f1.y);
        a[6] = (short)f2bf(f1.z); a[7] = (short)f2bf(f1.w);
        afrag[kc] = a;
    }

    f32x4 acc[3][4] = {};
#pragma unroll
    for (int kc = 0; kc < 4; ++kc) {
#pragma unroll
        for (int mat = 0; mat < 3; ++mat) {
#pragma unroll
            for (int ct = 0; ct < 4; ++ct) {
                short8 bfrag = *(const short8*)(
                    Wpack + (size_t)(((mat * 4 + ct) * 4 + kc) << 9) + lane * 8);
                acc[mat][ct] = __builtin_amdgcn_mfma_f32_16x16x32_bf16(
                    afrag[kc], bfrag, acc[mat][ct], 0, 0, 0);
            }
        }
    }

    // C/D layout: local row = lg*4 + r, col = ct*16 + lr   [m89 verified]
#pragma unroll
    for (int r = 0; r < 4; ++r) {
        int gr = row0 + lg * 4 + r;
        if (gr < N_NODES) {
#pragma unroll
            for (int ct = 0; ct < 4; ++ct) {
                unsigned pk = f2bf(acc[0][ct][r]) | (f2bf(acc[1][ct][r]) << 16);
                wxi[(size_t)gr * OUT_DIM + ct * 16 + lr] = pk;
                xres[(size_t)gr * OUT_DIM + ct * 16 + lr] = acc[2][ct][r];
            }
        }
    }

    // al/ar epilogue: dot over 64 cols = per-lane partial over ct + 16-lane reduce
#pragma unroll
    for (int mat = 0; mat < 2; ++mat) {
#pragma unroll
        for (int s = 0; s < 3; ++s) {
            float wlv[4], wrv[4];
#pragma unroll
            for (int ct = 0; ct < 4; ++ct) {
                wlv[ct] = wl[(size_t)(mat * 3 + s) * OUT_DIM + ct * 16 + lr];
                wrv[ct] = wr[(size_t)(mat * 3 + s) * OUT_DIM + ct * 16 + lr];
            }
#pragma unroll
            for (int r = 0; r < 4; ++r) {
                float pl = 0.f, pr = 0.f;
#pragma unroll
                for (int ct = 0; ct < 4; ++ct) {
                    pl = fmaf(acc[mat][ct][r], wlv[ct], pl);
                    pr = fmaf(acc[mat][ct][r], wrv[ct], pr);
                }
#pragma unroll
                for (int off = 1; off < 16; off <<= 1) {
                    pl += __shfl_xor(pl, off);
                    pr += __shfl_xor(pr, off);
                }
                if (lr == 0) {
                    int gr = row0 + lg * 4 + r;
                    if (gr < N_NODES) {
                        al[(size_t)gr * 6 + mat * 3 + s] = pl;
                        ar[(size_t)gr * 6 + mat * 3 + s] = pr;
                    }
                }
            }
        }
    }
}

// ---------------------------------------------------------------------------
// CSR build
// ---------------------------------------------------------------------------
__global__ void hist_kernel(const int* __restrict__ rows, int* __restrict__ deg) {
    int e = blockIdx.x * 256 + threadIdx.x;
    if (e >= N_EDGES) return;
    atomicAdd(&deg[rows[e]], 1);
}

__global__ void scan1_kernel(const int* __restrict__ deg, int* __restrict__ bsum) {
    __shared__ int sh[256];
    int t = threadIdx.x;
    int i = blockIdx.x * 256 + t;
    sh[t] = (i < N_NODES) ? deg[i] : 0;
    __syncthreads();
    for (int off = 128; off > 0; off >>= 1) {
        if (t < off) sh[t] += sh[t + off];
        __syncthreads();
    }
    if (t == 0) bsum[blockIdx.x] = sh[0];
}

// fused: block-prefix over bsum + intra-block Hillis-Steele scan
__global__ void scan3_kernel(const int* __restrict__ deg,
                             const int* __restrict__ bsum,
                             int* __restrict__ row_ptr,
                             int* __restrict__ cursor) {
    __shared__ int pref[256];
    __shared__ int sh[256];
    int t = threadIdx.x;
    pref[t] = (t < (int)blockIdx.x && t < NB_SCAN) ? bsum[t] : 0;
    __syncthreads();
    for (int off = 128; off > 0; off >>= 1) {
        if (t < off) pref[t] += pref[t + off];
        __syncthreads();
    }
    int bpre = pref[0];
    int i = blockIdx.x * 256 + t;
    int v = (i < N_NODES) ? deg[i] : 0;
    sh[t] = v;
    int val = v;
    __syncthreads();
    for (int off = 1; off < 256; off <<= 1) {
        int y = (t >= off) ? sh[t - off] : 0;
        __syncthreads();
        val += y;
        sh[t] = val;
        __syncthreads();
    }
    if (i < N_NODES) {
        int rp = bpre + val - v;   // exclusive prefix
        row_ptr[i] = rp;
        cursor[i] = rp;
    }
    if (blockIdx.x == 0 && t == 0) row_ptr[N_NODES] = N_EDGES;
}

// ---------------------------------------------------------------------------
// Scatter + fused score: one 16B packed record {col, s0, s1, 0} per edge.
// ---------------------------------------------------------------------------
__global__ void scatter_score_kernel(const int* __restrict__ rows,
                                     const int* __restrict__ cols,
                                     const float* __restrict__ atten,
                                     const float* __restrict__ support,
                                     const float* __restrict__ al,
                                     const float* __restrict__ ar,
                                     int* __restrict__ cursor,
                                     uint4* __restrict__ edata) {
    int e = blockIdx.x * 256 + threadIdx.x;
    if (e >= N_EDGES) return;
    int r = rows[e], c = cols[e];
    float a0  = atten[e];
    float a1  = atten[N_EDGES + e];
    float sp0 = support[e];
    float sp1 = support[N_EDGES + e];
    const float* alr = al + (size_t)r * 6;
    const float* arc = ar + (size_t)c * 6;
    float sc0 = (alr[0] + arc[0]) * a0 + (alr[1] + arc[1]) * a1 + (alr[2] + arc[2]) * sp0;
    float sc1 = (alr[3] + arc[3]) * a0 + (alr[4] + arc[4]) * a1 + (alr[5] + arc[5]) * sp1;
    int pos = atomicAdd(&cursor[r], 1);
    uint4 pv;
    pv.x = (unsigned)c;
    pv.y = __float_as_uint(sc0);
    pv.z = __float_as_uint(sc1);
    pv.w = 0u;
    edata[pos] = pv;
}

// ---------------------------------------------------------------------------
// Fused softmax + SpMM + residual + elu: one wave per row.
// ---------------------------------------------------------------------------
__global__ void attn_kernel(const int* __restrict__ row_ptr,
                            const uint4* __restrict__ edata,
                            const unsigned* __restrict__ wxi,
                            const float* __restrict__ xres,
                            const float* __restrict__ Wres,
                            float* __restrict__ out) {
    int wid = blockIdx.x * 4 + (threadIdx.x >> 6);
    if (wid >= N_NODES) return;
    int lane = threadIdx.x & 63;
    int beg = row_ptr[wid], end = row_ptr[wid + 1];
    int deg = end - beg;
    float a = 0.f;

    if (deg > 0 && deg <= 64) {
        bool valid = lane < deg;
        uint4 ed = edata[valid ? beg + lane : beg];
        unsigned c = ed.x;
        float sc0 = valid ? __uint_as_float(ed.y) : NEG_INF;
        float sc1 = valid ? __uint_as_float(ed.z) : NEG_INF;
        float m0 = sc0, m1 = sc1;
#pragma unroll
        for (int off = 32; off > 0; off >>= 1) {
            m0 = fmaxf(m0, __shfl_xor(m0, off));
            m1 = fmaxf(m1, __shfl_xor(m1, off));
        }
        float e0 = valid ? __expf(sc0 - m0) : 0.f;
        float e1 = valid ? __expf(sc1 - m1) : 0.f;
        float l0 = e0, l1 = e1;
#pragma unroll
        for (int off = 32; off > 0; off >>= 1) {
            l0 += __shfl_xor(l0, off);
            l1 += __shfl_xor(l1, off);
        }
        float p0 = e0 / l0;
        float p1 = e1 / l1;
        float a0 = 0.f, a1 = 0.f, a2 = 0.f, a3 = 0.f;
        int i = 0;
        for (; i + 4 <= deg; i += 4) {
            unsigned c0 = rl_u(c, i),     c1 = rl_u(c, i + 1);
            unsigned c2 = rl_u(c, i + 2), c3 = rl_u(c, i + 3);
            unsigned v0 = wxi[(size_t)c0 * OUT_DIM + lane];
            unsigned v1 = wxi[(size_t)c1 * OUT_DIM + lane];
            unsigned v2 = wxi[(size_t)c2 * OUT_DIM + lane];
            unsigned v3 = wxi[(size_t)c3 * OUT_DIM + lane];
            a0 = fmaf(rl_f(p0, i),     __uint_as_float(v0 << 16), a0);
            a0 = fmaf(rl_f(p1, i),     __uint_as_float(v0 & 0xffff0000u), a0);
            a1 = fmaf(rl_f(p0, i + 1), __uint_as_float(v1 << 16), a1);
            a1 = fmaf(rl_f(p1, i + 1), __uint_as_float(v1 & 0xffff0000u), a1);
            a2 = fmaf(rl_f(p0, i + 2), __uint_as_float(v2 << 16), a2);
            a2 = fmaf(rl_f(p1, i + 2), __uint_as_float(v2 & 0xffff0000u), a2);
            a3 = fmaf(rl_f(p0, i + 3), __uint_as_float(v3 << 16), a3);
            a3 = fmaf(rl_f(p1, i + 3), __uint_as_float(v3 & 0xffff0000u), a3);
        }
        for (; i < deg; ++i) {
            unsigned ci = rl_u(c, i);
            unsigned v = wxi[(size_t)ci * OUT_DIM + lane];
            a0 = fmaf(rl_f(p0, i), __uint_as_float(v << 16), a0);
            a0 = fmaf(rl_f(p1, i), __uint_as_float(v & 0xffff0000u), a0);
        }
        a = (a0 + a1) + (a2 + a3);
    } else if (deg > 64) {
        // rare long-row path: online softmax, then chunked spmm
        float m0 = NEG_INF, l0 = 0.f, m1 = NEG_INF, l1 = 0.f;
        for (int base = beg; base < end; base += 64) {
            int pos = base + lane;
            bool valid = pos < end;
            uint4 ed = edata[valid ? pos : beg];
            float sc0 = valid ? __uint_as_float(ed.y) : NEG_INF;
            float sc1 = valid ? __uint_as_float(ed.z) : NEG_INF;
            float cm0 = sc0, cm1 = sc1;
#pragma unroll
            for (int off = 32; off > 0; off >>= 1) {
                cm0 = fmaxf(cm0, __shfl_xor(cm0, off));
                cm1 = fmaxf(cm1, __shfl_xor(cm1, off));
            }
            float mn0 = fmaxf(m0, cm0), mn1 = fmaxf(m1, cm1);
            float e0 = valid ? __expf(sc0 - mn0) : 0.f;
            float e1 = valid ? __expf(sc1 - mn1) : 0.f;
#pragma unroll
            for (int off = 32; off > 0; off >>= 1) {
                e0 += __shfl_xor(e0, off);
                e1 += __shfl_xor(e1, off);
            }
            l0 = l0 * __expf(m0 - mn0) + e0;
            l1 = l1 * __expf(m1 - mn1) + e1;
            m0 = mn0; m1 = mn1;
        }
        float inv0 = 1.f / l0, inv1 = 1.f / l1;
        for (int base = beg; base < end; base += 64) {
            int pos = base + lane;
            bool valid = pos < end;
            uint4 ed = edata[valid ? pos : beg];
            unsigned c = ed.x;
            float p0 = valid ? __expf(__uint_as_float(ed.y) - m0) * inv0 : 0.f;
            float p1 = valid ? __expf(__uint_as_float(ed.z) - m1) * inv1 : 0.f;
            int cnt = min(64, end - base);
            for (int i = 0; i < cnt; ++i) {
                unsigned ci = rl_u(c, i);
                unsigned v = wxi[(size_t)ci * OUT_DIM + lane];
                a = fmaf(rl_f(p0, i), __uint_as_float(v << 16), a);
                a = fmaf(rl_f(p1, i), __uint_as_float(v & 0xffff0000u), a);
            }
        }
    }

    // residual: out = elu(xres + acc @ Wres[128:]) ; readlane broadcasts
    const float* Wres2 = Wres + (size_t)IN_DIM * OUT_DIM;
    float r = xres[(size_t)wid * OUT_DIM + lane];
#pragma unroll
    for (int d = 0; d < OUT_DIM; ++d) {
        float ad = rl_f(a, d);
        r = fmaf(ad, Wres2[d * OUT_DIM + lane], r);
    }
    out[(size_t)wid * OUT_DIM + lane] = (r > 0.f) ? r : expm1f(r);
}

extern "C" void kernel_launch(void* const* d_in, const int* in_sizes, int n_in,
                              void* d_out, int out_size, void* d_ws, size_t ws_size,
                              hipStream_t stream) {
    const float* x       = (const float*)d_in[0];
    const float* support = (const float*)d_in[1];
    const float* atten   = (const float*)d_in[2];
    const float* Wt      = (const float*)d_in[3];
    const float* wl      = (const float*)d_in[4];
    const float* wr      = (const float*)d_in[5];
    const float* Wres    = (const float*)d_in[6];
    const int*   rows    = (const int*)d_in[7];
    const int*   cols    = (const int*)d_in[8];
    float* out = (float*)d_out;

    // workspace layout (16B-aligned sections)
    unsigned* wxi  = (unsigned*)d_ws;                                  // N*64 packed
    float* xres    = (float*)(wxi + (size_t)N_NODES * OUT_DIM);        // N*64
    float* al      = xres + (size_t)N_NODES * OUT_DIM;                 // N*6
    float* ar      = al + (size_t)N_NODES * 6;                         // N*6
    uint4* edata   = (uint4*)(ar + (size_t)N_NODES * 6);               // E * 16B
    int*   deg     = (int*)(edata + (size_t)N_EDGES);                  // N
    int*   row_ptr = deg + N_NODES;                                    // N+1
    int*   cursor  = row_ptr + N_NODES + 1;                            // N
    int*   bsum    = cursor + N_NODES;                                 // NB_SCAN
    ushort_t* Wpack = (ushort_t*)(bsum + NB_SCAN + 4);                 // 24576 bf16

    hipMemsetAsync(deg, 0, (size_t)N_NODES * sizeof(int), stream);

    wpack_kernel<<<(3 * 16 * 512 + 255) / 256, 256, 0, stream>>>(Wt, Wres, (ushort_t*)Wpack);
    gemm_kernel<<<GBLK, 256, 0, stream>>>(x, (const ushort_t*)Wpack, wl, wr,
                                          wxi, xres, al, ar);
    hist_kernel<<<(N_EDGES + 255) / 256, 256, 0, stream>>>(rows, deg);
    scan1_kernel<<<NB_SCAN, 256, 0, stream>>>(deg, bsum);
    scan3_kernel<<<NB_SCAN, 256, 0, stream>>>(deg, bsum, row_ptr, cursor);
    scatter_score_kernel<<<(N_EDGES + 255) / 256, 256, 0, stream>>>(
        rows, cols, atten, support, al, ar, cursor, edata);
    attn_kernel<<<(N_NODES + 3) / 4, 256, 0, stream>>>(
        row_ptr, edata, wxi, xres, Wres, out);
}

// Round 7
// 163.976 us; speedup vs baseline: 5.1638x; 1.0180x over previous
//
#include <hip/hip_runtime.h>

#define N_NODES 50000
#define N_EDGES 800000
#define IN_DIM 128
#define OUT_DIM 64
#define NEG_INF (-1e30f)
#define GBLK ((N_NODES + 63) / 64)           // 782
#define BSHIFT 8
#define NBUK ((N_NODES + 255) >> 8)          // 196
#define EB 1024
#define PREB ((N_EDGES + EB - 1) / EB)       // 782

typedef unsigned short ushort_t;
typedef __attribute__((ext_vector_type(8))) short short8;
typedef __attribute__((ext_vector_type(4))) float f32x4;

__device__ __forceinline__ unsigned f2bf(float f) {
    unsigned u = __float_as_uint(f);
    u += 0x7fffu + ((u >> 16) & 1u);         // round-to-nearest-even
    return u >> 16;
}
__device__ __forceinline__ unsigned rl_u(unsigned v, int i) {
    return __builtin_amdgcn_readlane(v, i);
}
__device__ __forceinline__ float rl_f(float v, int i) {
    return __uint_as_float(__builtin_amdgcn_readlane(__float_as_uint(v), i));
}

// ---------------------------------------------------------------------------
// Pack the 3 weight matrices into MFMA B-fragment order (bf16).
// ---------------------------------------------------------------------------
__global__ void wpack_kernel(const float* __restrict__ Wt,
                             const float* __restrict__ Wres,
                             ushort_t* __restrict__ Wpack) {
    int idx = blockIdx.x * 256 + threadIdx.x;   // 0 .. 24575
    if (idx >= 3 * 16 * 512) return;
    int f = idx >> 9;
    int within = idx & 511;
    int lane = within >> 3;
    int b = within & 7;
    int mat = f >> 4;
    int ct = (f >> 2) & 3;
    int kc = f & 3;
    int k = kc * 32 + (lane >> 4) * 8 + b;
    int c = ct * 16 + (lane & 15);
    const float* W = (mat < 2) ? (Wt + (size_t)mat * IN_DIM * OUT_DIM) : Wres;
    Wpack[idx] = (ushort_t)f2bf(W[(size_t)k * OUT_DIM + c]);
}

// ---------------------------------------------------------------------------
// Fused: MFMA GEMM (blocks 0..GBLK-1) + coarse bucket histogram (rest).
// ---------------------------------------------------------------------------
__global__ __launch_bounds__(256) void gemm_hist_kernel(
        const float* __restrict__ x,
        const ushort_t* __restrict__ Wpack,
        const float* __restrict__ wl,
        const float* __restrict__ wr,
        unsigned* __restrict__ wxi,
        float* __restrict__ xres,
        float* __restrict__ al,
        float* __restrict__ ar,
        const int* __restrict__ rows,
        int* __restrict__ bhist) {
    if (blockIdx.x >= GBLK) {
        // ---- coarse bucket histogram over 1024 edges ----
        __shared__ int sh[NBUK];
        int t = threadIdx.x;
        for (int i = t; i < NBUK; i += 256) sh[i] = 0;
        __syncthreads();
        int b0 = (blockIdx.x - GBLK) * EB;
#pragma unroll
        for (int i = 0; i < EB / 256; ++i) {
            int e = b0 + i * 256 + t;
            if (e < N_EDGES) atomicAdd(&sh[rows[e] >> BSHIFT], 1);
        }
        __syncthreads();
        for (int i = t; i < NBUK; i += 256)
            if (sh[i]) atomicAdd(&bhist[i], sh[i]);
        return;
    }

    int wave = threadIdx.x >> 6;
    int lane = threadIdx.x & 63;
    int lr = lane & 15;
    int lg = lane >> 4;
    int row0 = blockIdx.x * 64 + wave * 16;

    int arow = row0 + lr;
    if (arow >= N_NODES) arow = N_NODES - 1;
    const float* xr = x + (size_t)arow * IN_DIM;
    short8 afrag[4];
#pragma unroll
    for (int kc = 0; kc < 4; ++kc) {
        float4 f0 = *(const float4*)(xr + kc * 32 + lg * 8);
        float4 f1 = *(const float4*)(xr + kc * 32 + lg * 8 + 4);
        short8 a;
        a[0] = (short)f2bf(f0.x); a[1] = (short)f2bf(f0.y);
        a[2] = (short)f2bf(f0.z); a[3] = (short)f2bf(f0.w);
        a[4] = (short)f2bf(f1.x); a[5] = (short)f2bf(f1.y);
        a[6] = (short)f2bf(f1.z); a[7] = (short)f2bf(f1.w);
        afrag[kc] = a;
    }

    f32x4 acc[3][4] = {};
#pragma unroll
    for (int kc = 0; kc < 4; ++kc) {
#pragma unroll
        for (int mat = 0; mat < 3; ++mat) {
#pragma unroll
            for (int ct = 0; ct < 4; ++ct) {
                short8 bfrag = *(const short8*)(
                    Wpack + (size_t)(((mat * 4 + ct) * 4 + kc) << 9) + lane * 8);
                acc[mat][ct] = __builtin_amdgcn_mfma_f32_16x16x32_bf16(
                    afrag[kc], bfrag, acc[mat][ct], 0, 0, 0);
            }
        }
    }

    // C/D: local row = lg*4 + r, col = ct*16 + lr
#pragma unroll
    for (int r = 0; r < 4; ++r) {
        int gr = row0 + lg * 4 + r;
        if (gr < N_NODES) {
#pragma unroll
            for (int ct = 0; ct < 4; ++ct) {
                unsigned pk = f2bf(acc[0][ct][r]) | (f2bf(acc[1][ct][r]) << 16);
                wxi[(size_t)gr * OUT_DIM + ct * 16 + lr] = pk;
                xres[(size_t)gr * OUT_DIM + ct * 16 + lr] = acc[2][ct][r];
            }
        }
    }

    // al/ar epilogue
#pragma unroll
    for (int mat = 0; mat < 2; ++mat) {
#pragma unroll
        for (int s = 0; s < 3; ++s) {
            float wlv[4], wrv[4];
#pragma unroll
            for (int ct = 0; ct < 4; ++ct) {
                wlv[ct] = wl[(size_t)(mat * 3 + s) * OUT_DIM + ct * 16 + lr];
                wrv[ct] = wr[(size_t)(mat * 3 + s) * OUT_DIM + ct * 16 + lr];
            }
#pragma unroll
            for (int r = 0; r < 4; ++r) {
                float pl = 0.f, pr = 0.f;
#pragma unroll
                for (int ct = 0; ct < 4; ++ct) {
                    pl = fmaf(acc[mat][ct][r], wlv[ct], pl);
                    pr = fmaf(acc[mat][ct][r], wrv[ct], pr);
                }
#pragma unroll
                for (int off = 1; off < 16; off <<= 1) {
                    pl += __shfl_xor(pl, off);
                    pr += __shfl_xor(pr, off);
                }
                if (lr == 0) {
                    int gr = row0 + lg * 4 + r;
                    if (gr < N_NODES) {
                        al[(size_t)gr * 6 + mat * 3 + s] = pl;
                        ar[(size_t)gr * 6 + mat * 3 + s] = pr;
                    }
                }
            }
        }
    }
}

// ---------------------------------------------------------------------------
// Exclusive scan of bucket histogram -> bbase (fixed) + gcursor (working).
// ---------------------------------------------------------------------------
__global__ void bscan_kernel(const int* __restrict__ bhist,
                             int* __restrict__ bbase,
                             int* __restrict__ gcursor) {
    __shared__ int sh[256];
    int t = threadIdx.x;
    int v = (t < NBUK) ? bhist[t] : 0;
    sh[t] = v;
    int val = v;
    __syncthreads();
    for (int off = 1; off < 256; off <<= 1) {
        int y = (t >= off) ? sh[t - off] : 0;
        __syncthreads();
        val += y;
        sh[t] = val;
        __syncthreads();
    }
    if (t < NBUK) {
        int ex = val - v;
        bbase[t] = ex;
        gcursor[t] = ex;
    }
}

// ---------------------------------------------------------------------------
// Pass A: fused score + bucket scatter. Per 1024-edge block: LDS bucket
// histogram, one global run-reservation atomic per (block,bucket), then
// records written into block-local runs (L2-friendly, lines fill locally).
// Record: {c | rl<<16, s0, s1, 0}.
// ---------------------------------------------------------------------------
__global__ __launch_bounds__(256) void score_bucket_kernel(
        const int* __restrict__ rows,
        const int* __restrict__ cols,
        const float* __restrict__ atten,
        const float* __restrict__ support,
        const float* __restrict__ al,
        const float* __restrict__ ar,
        int* __restrict__ gcursor,
        uint4* __restrict__ etmp) {
    __shared__ int hist[NBUK];
    __shared__ int rbase[NBUK];
    __shared__ int lcnt[NBUK];
    int t = threadIdx.x;
    for (int i = t; i < NBUK; i += 256) { hist[i] = 0; lcnt[i] = 0; }
    __syncthreads();
    int base0 = blockIdx.x * EB;
    int r_[EB / 256];
#pragma unroll
    for (int i = 0; i < EB / 256; ++i) {
        int e = base0 + i * 256 + t;
        int r = (e < N_EDGES) ? rows[e] : -1;
        r_[i] = r;
        if (r >= 0) atomicAdd(&hist[r >> BSHIFT], 1);
    }
    __syncthreads();
    for (int i = t; i < NBUK; i += 256)
        rbase[i] = hist[i] ? atomicAdd(&gcursor[i], hist[i]) : 0;
    __syncthreads();
#pragma unroll
    for (int i = 0; i < EB / 256; ++i) {
        int e = base0 + i * 256 + t;
        int r = r_[i];
        if (r < 0) continue;
        int c = cols[e];
        float a0  = atten[e];
        float a1  = atten[N_EDGES + e];
        float sp0 = support[e];
        float sp1 = support[N_EDGES + e];
        const float* alr = al + (size_t)r * 6;
        const float* arc = ar + (size_t)c * 6;
        float sc0 = (alr[0] + arc[0]) * a0 + (alr[1] + arc[1]) * a1 + (alr[2] + arc[2]) * sp0;
        float sc1 = (alr[3] + arc[3]) * a0 + (alr[4] + arc[4]) * a1 + (alr[5] + arc[5]) * sp1;
        int b = r >> BSHIFT;
        int pos = rbase[b] + atomicAdd(&lcnt[b], 1);
        uint4 pv;
        pv.x = (unsigned)c | ((unsigned)(r & 255) << 16);
        pv.y = __float_as_uint(sc0);
        pv.z = __float_as_uint(sc1);
        pv.w = 0u;
        etmp[pos] = pv;
    }
}

// ---------------------------------------------------------------------------
// Pass B: per-bucket counting sort into final CSR edata + row_ptr.
// Bucket region is contiguous; reads and writes are bucket-local.
// ---------------------------------------------------------------------------
__global__ __launch_bounds__(256) void bucket_sort_kernel(
        const int* __restrict__ bbase,
        const int* __restrict__ gcursor,
        const uint4* __restrict__ etmp,
        uint4* __restrict__ edata,
        int* __restrict__ row_ptr) {
    __shared__ int sh[256];
    __shared__ int start[256];
    __shared__ int cnt[256];
    int b = blockIdx.x;
    int t = threadIdx.x;
    int base = bbase[b];
    int nb = gcursor[b] - base;   // bucket count (gcursor advanced by pass A)
    sh[t] = 0; cnt[t] = 0;
    __syncthreads();
    for (int i = t; i < nb; i += 256) {
        unsigned meta = etmp[base + i].x;
        atomicAdd(&sh[(meta >> 16) & 255], 1);
    }
    __syncthreads();
    int v = sh[t];
    __syncthreads();
    sh[t] = v;
    int val = v;
    __syncthreads();
    for (int off = 1; off < 256; off <<= 1) {
        int y = (t >= off) ? sh[t - off] : 0;
        __syncthreads();
        val += y;
        sh[t] = val;
        __syncthreads();
    }
    start[t] = val - v;   // exclusive prefix
    __syncthreads();
    int row = (b << BSHIFT) + t;
    if (row < N_NODES) row_ptr[row] = base + start[t];
    if (b == NBUK - 1 && t == 0) row_ptr[N_NODES] = N_EDGES;
    for (int i = t; i < nb; i += 256) {
        uint4 rec = etmp[base + i];
        int rl = (rec.x >> 16) & 255;
        int pos = base + start[rl] + atomicAdd(&cnt[rl], 1);
        edata[pos] = rec;
    }
}

// ---------------------------------------------------------------------------
// Fused softmax + SpMM + residual + elu: one wave per row.
// ---------------------------------------------------------------------------
__global__ void attn_kernel(const int* __restrict__ row_ptr,
                            const uint4* __restrict__ edata,
                            const unsigned* __restrict__ wxi,
                            const float* __restrict__ xres,
                            const float* __restrict__ Wres,
                            float* __restrict__ out) {
    int wid = blockIdx.x * 4 + (threadIdx.x >> 6);
    if (wid >= N_NODES) return;
    int lane = threadIdx.x & 63;
    int beg = row_ptr[wid], end = row_ptr[wid + 1];
    int deg = end - beg;
    float a = 0.f;

    if (deg > 0 && deg <= 64) {
        bool valid = lane < deg;
        uint4 ed = edata[valid ? beg + lane : beg];
        unsigned c = ed.x & 0xFFFFu;
        float sc0 = valid ? __uint_as_float(ed.y) : NEG_INF;
        float sc1 = valid ? __uint_as_float(ed.z) : NEG_INF;
        float m0 = sc0, m1 = sc1;
#pragma unroll
        for (int off = 32; off > 0; off >>= 1) {
            m0 = fmaxf(m0, __shfl_xor(m0, off));
            m1 = fmaxf(m1, __shfl_xor(m1, off));
        }
        float e0 = valid ? __expf(sc0 - m0) : 0.f;
        float e1 = valid ? __expf(sc1 - m1) : 0.f;
        float l0 = e0, l1 = e1;
#pragma unroll
        for (int off = 32; off > 0; off >>= 1) {
            l0 += __shfl_xor(l0, off);
            l1 += __shfl_xor(l1, off);
        }
        float p0 = e0 / l0;
        float p1 = e1 / l1;
        float a0 = 0.f, a1 = 0.f, a2 = 0.f, a3 = 0.f;
        int i = 0;
        for (; i + 4 <= deg; i += 4) {
            unsigned c0 = rl_u(c, i),     c1 = rl_u(c, i + 1);
            unsigned c2 = rl_u(c, i + 2), c3 = rl_u(c, i + 3);
            unsigned v0 = wxi[(size_t)c0 * OUT_DIM + lane];
            unsigned v1 = wxi[(size_t)c1 * OUT_DIM + lane];
            unsigned v2 = wxi[(size_t)c2 * OUT_DIM + lane];
            unsigned v3 = wxi[(size_t)c3 * OUT_DIM + lane];
            a0 = fmaf(rl_f(p0, i),     __uint_as_float(v0 << 16), a0);
            a0 = fmaf(rl_f(p1, i),     __uint_as_float(v0 & 0xffff0000u), a0);
            a1 = fmaf(rl_f(p0, i + 1), __uint_as_float(v1 << 16), a1);
            a1 = fmaf(rl_f(p1, i + 1), __uint_as_float(v1 & 0xffff0000u), a1);
            a2 = fmaf(rl_f(p0, i + 2), __uint_as_float(v2 << 16), a2);
            a2 = fmaf(rl_f(p1, i + 2), __uint_as_float(v2 & 0xffff0000u), a2);
            a3 = fmaf(rl_f(p0, i + 3), __uint_as_float(v3 << 16), a3);
            a3 = fmaf(rl_f(p1, i + 3), __uint_as_float(v3 & 0xffff0000u), a3);
        }
        for (; i < deg; ++i) {
            unsigned ci = rl_u(c, i);
            unsigned v = wxi[(size_t)ci * OUT_DIM + lane];
            a0 = fmaf(rl_f(p0, i), __uint_as_float(v << 16), a0);
            a0 = fmaf(rl_f(p1, i), __uint_as_float(v & 0xffff0000u), a0);
        }
        a = (a0 + a1) + (a2 + a3);
    } else if (deg > 64) {
        float m0 = NEG_INF, l0 = 0.f, m1 = NEG_INF, l1 = 0.f;
        for (int base = beg; base < end; base += 64) {
            int pos = base + lane;
            bool valid = pos < end;
            uint4 ed = edata[valid ? pos : beg];
            float sc0 = valid ? __uint_as_float(ed.y) : NEG_INF;
            float sc1 = valid ? __uint_as_float(ed.z) : NEG_INF;
            float cm0 = sc0, cm1 = sc1;
#pragma unroll
            for (int off = 32; off > 0; off >>= 1) {
                cm0 = fmaxf(cm0, __shfl_xor(cm0, off));
                cm1 = fmaxf(cm1, __shfl_xor(cm1, off));
            }
            float mn0 = fmaxf(m0, cm0), mn1 = fmaxf(m1, cm1);
            float e0 = valid ? __expf(sc0 - mn0) : 0.f;
            float e1 = valid ? __expf(sc1 - mn1) : 0.f;
#pragma unroll
            for (int off = 32; off > 0; off >>= 1) {
                e0 += __shfl_xor(e0, off);
                e1 += __shfl_xor(e1, off);
            }
            l0 = l0 * __expf(m0 - mn0) + e0;
            l1 = l1 * __expf(m1 - mn1) + e1;
            m0 = mn0; m1 = mn1;
        }
        float inv0 = 1.f / l0, inv1 = 1.f / l1;
        for (int base = beg; base < end; base += 64) {
            int pos = base + lane;
            bool valid = pos < end;
            uint4 ed = edata[valid ? pos : beg];
            unsigned c = ed.x & 0xFFFFu;
            float p0 = valid ? __expf(__uint_as_float(ed.y) - m0) * inv0 : 0.f;
            float p1 = valid ? __expf(__uint_as_float(ed.z) - m1) * inv1 : 0.f;
            int cnt = min(64, end - base);
            for (int i = 0; i < cnt; ++i) {
                unsigned ci = rl_u(c, i);
                unsigned v = wxi[(size_t)ci * OUT_DIM + lane];
                a = fmaf(rl_f(p0, i), __uint_as_float(v << 16), a);
                a = fmaf(rl_f(p1, i), __uint_as_float(v & 0xffff0000u), a);
            }
        }
    }

    // residual: out = elu(xres + acc @ Wres[128:])
    const float* Wres2 = Wres + (size_t)IN_DIM * OUT_DIM;
    float r = xres[(size_t)wid * OUT_DIM + lane];
#pragma unroll
    for (int d = 0; d < OUT_DIM; ++d) {
        float ad = rl_f(a, d);
        r = fmaf(ad, Wres2[d * OUT_DIM + lane], r);
    }
    out[(size_t)wid * OUT_DIM + lane] = (r > 0.f) ? r : expm1f(r);
}

extern "C" void kernel_launch(void* const* d_in, const int* in_sizes, int n_in,
                              void* d_out, int out_size, void* d_ws, size_t ws_size,
                              hipStream_t stream) {
    const float* x       = (const float*)d_in[0];
    const float* support = (const float*)d_in[1];
    const float* atten   = (const float*)d_in[2];
    const float* Wt      = (const float*)d_in[3];
    const float* wl      = (const float*)d_in[4];
    const float* wr      = (const float*)d_in[5];
    const float* Wres    = (const float*)d_in[6];
    const int*   rows    = (const int*)d_in[7];
    const int*   cols    = (const int*)d_in[8];
    float* out = (float*)d_out;

    // workspace layout (16B-aligned sections)
    unsigned* wxi   = (unsigned*)d_ws;                                 // N*64
    float* xres     = (float*)(wxi + (size_t)N_NODES * OUT_DIM);       // N*64
    float* al       = xres + (size_t)N_NODES * OUT_DIM;                // N*6
    float* ar       = al + (size_t)N_NODES * 6;                        // N*6
    uint4* etmp     = (uint4*)(ar + (size_t)N_NODES * 6);              // E
    uint4* edata    = etmp + (size_t)N_EDGES;                          // E
    int*   row_ptr  = (int*)(edata + (size_t)N_EDGES);                 // N+1
    int*   bhist    = row_ptr + N_NODES + 1;                           // NBUK
    int*   bbase    = bhist + NBUK;                                    // NBUK
    int*   gcursor  = bbase + NBUK;                                    // NBUK
    ushort_t* Wpack = (ushort_t*)(gcursor + NBUK + 4);                 // 24576

    hipMemsetAsync(bhist, 0, NBUK * sizeof(int), stream);

    wpack_kernel<<<(3 * 16 * 512 + 255) / 256, 256, 0, stream>>>(Wt, Wres, Wpack);
    gemm_hist_kernel<<<GBLK + PREB, 256, 0, stream>>>(
        x, Wpack, wl, wr, wxi, xres, al, ar, rows, bhist);
    bscan_kernel<<<1, 256, 0, stream>>>(bhist, bbase, gcursor);
    score_bucket_kernel<<<PREB, 256, 0, stream>>>(
        rows, cols, atten, support, al, ar, gcursor, etmp);
    bucket_sort_kernel<<<NBUK, 256, 0, stream>>>(
        bbase, gcursor, etmp, edata, row_ptr);
    attn_kernel<<<(N_NODES + 3) / 4, 256, 0, stream>>>(
        row_ptr, edata, wxi, xres, Wres, out);
}